// Round 3
// baseline (389.162 us; speedup 1.0000x reference)
//
#include <hip/hip_runtime.h>
#include <math.h>

// SelfAttentionLayer B=4, N=2048, D=E=1024, fp32 in/out.
// out[b,j,e] = sum_i softmax_i(q_i . k_j / 32) * v[b,i,e]
// R12: qkv re-tiled 256x384 (grid 32x8 = 256 blocks EXACT -> kills R11's
//      1.5-round tail, 25% of qkv time). LDS 160KB (A 2x32K, B 2x48K).
//      Same proven 8-phase window schedule, vmcnt(5) at ph4/ph8.
//      Both cores now cache B fragments in regs (bfA/bfB) -> B loaded once
//      per K-tile: 384-core 28 reads/192 MFMA, 256-core 24 reads/128 MFMA.
//
// ws (ushort): xb[8M] Wqkvt[3M] QKb[16M] Vtb[8M] Pb[16M] l[8192 f32].

typedef __bf16 bf16x8 __attribute__((ext_vector_type(8)));
typedef float f32x4 __attribute__((ext_vector_type(4)));

static __device__ __forceinline__ unsigned short f2bf(float f) {
    unsigned u = __float_as_uint(f);
    u += 0x7fff + ((u >> 16) & 1);   // round-to-nearest-even
    return (unsigned short)(u >> 16);
}

#define GLDS16(gptr, lptr)                                                            \
    __builtin_amdgcn_global_load_lds(                                                 \
        (const __attribute__((address_space(1))) void*)(gptr),                        \
        (__attribute__((address_space(3))) void*)(lptr), 16, 0, 0)

#define BARSYNC  __builtin_amdgcn_s_barrier()
#define WAITLGKM do { asm volatile("s_waitcnt lgkmcnt(0)" ::: "memory");    \
                      __builtin_amdgcn_sched_barrier(0); } while (0)

// ===================== 256x256 8-phase GEMM core =====================
// (R11 structure, proven: conflicts 0. R12: B frags cached -> ph4/ph8 0-read)
// LDS 128KiB ushort map: A[buf][256][64] at buf*16384; B at 32768+buf*16384.
// Stage units: A(mh) rows {0,128}+mh*64..+63 ; B(nh) rows {0,64,128,192}+nh*32..+31
// Schedule (iter i: buf0=tile 2i, buf1=2i+1; t1=2i+1,t2=2i+2,t3=2i+3):
//  ph1(0,0,0):ldA0+ldB->bfA, STG_B(t1,0,b1)  ph5(1,0,0): same, STG_A(t2,1,b0)
//  ph2(0,0,1):ldB->bfB,      STG_A(t1,1,b1)  ph6(1,0,1): ldB->bfB, STG_B(t2,0,b0)
//  ph3(0,1,1):ldA1,          STG_A(t2,0,b0)  ph7(1,1,1): ldA1,     STG_A(t3,0,b1)
//  ph4(0,1,0):(no reads),    STG_B(t2,1,b0)  ph8(1,1,0): (none),   STG_B(t3,1,b1)
//  WAITV4 after ph4/ph8 MFMA. Every stage >=1 close-barrier after last read.
__device__ __forceinline__ void gemm256_core(
    const unsigned short* __restrict__ Ab,   // + gm0*ld
    const unsigned short* __restrict__ Bb,   // + gn0*ld
    const long ld, unsigned short* lds, f32x4 acc[8][4])
{
    const int tid  = threadIdx.x;
    const int w    = tid >> 6;
    const int lane = tid & 63;

    const int r  = lane >> 3;
    const int s  = lane & 7;
    const int cg = (s ^ r) * 8;

    const int fr    = lane & 15;
    const int quad  = lane >> 4;
    const int sw    = fr & 7;
    const int arow0 = (w >> 2) * 128;
    const int brow0 = (w & 3) * 64;

#define STG_A(t, mh, buf) do {                                              \
    const int rb_ = (w >> 2) * 128 + (mh) * 64 + (w & 3) * 16;              \
    const unsigned short* g_ = Ab + (long)(rb_ + r) * ld + (long)(t) * 64 + cg; \
    unsigned short* d_ = lds + (buf) * 16384 + rb_ * 64;                    \
    GLDS16(g_, d_); GLDS16(g_ + 8 * ld, d_ + 512); } while (0)
#define STG_B(t, nh, buf) do {                                              \
    const int rb_ = (w >> 1) * 64 + (nh) * 32 + (w & 1) * 16;               \
    const unsigned short* g_ = Bb + (long)(rb_ + r) * ld + (long)(t) * 64 + cg; \
    unsigned short* d_ = lds + 32768 + (buf) * 16384 + rb_ * 64;            \
    GLDS16(g_, d_); GLDS16(g_ + 8 * ld, d_ + 512); } while (0)

    bf16x8 af[4][2], bfA[2][2], bfB[2][2];
#define LOADA(buf, mh) do {                                                 \
    _Pragma("unroll") for (int ks_ = 0; ks_ < 2; ks_++)                     \
    _Pragma("unroll") for (int i_ = 0; i_ < 4; i_++)                        \
        af[i_][ks_] = *(const bf16x8*)&lds[(buf) * 16384 +                  \
            (arow0 + (mh) * 64 + i_ * 16 + fr) * 64 +                       \
            ((ks_ * 4 + quad) ^ sw) * 8]; } while (0)
#define LOADB(BF, buf, nh) do {                                             \
    _Pragma("unroll") for (int ks_ = 0; ks_ < 2; ks_++)                     \
    _Pragma("unroll") for (int j_ = 0; j_ < 2; j_++)                        \
        BF[j_][ks_] = *(const bf16x8*)&lds[32768 + (buf) * 16384 +          \
            (brow0 + (nh) * 32 + j_ * 16 + fr) * 64 +                       \
            ((ks_ * 4 + quad) ^ sw) * 8]; } while (0)

#define MFMA16(mh, nh, BF) do {                                             \
    __builtin_amdgcn_s_setprio(1);                                          \
    _Pragma("unroll") for (int ks_ = 0; ks_ < 2; ks_++)                     \
    _Pragma("unroll") for (int i_ = 0; i_ < 4; i_++)                        \
    _Pragma("unroll") for (int j_ = 0; j_ < 2; j_++)                        \
        acc[(mh) * 4 + i_][(nh) * 2 + j_] =                                 \
            __builtin_amdgcn_mfma_f32_16x16x32_bf16(                        \
                af[i_][ks_], BF[j_][ks_],                                   \
                acc[(mh) * 4 + i_][(nh) * 2 + j_], 0, 0, 0);                \
    __builtin_amdgcn_s_setprio(0); } while (0)

#pragma unroll
    for (int i = 0; i < 8; i++)
#pragma unroll
        for (int j = 0; j < 4; j++) acc[i][j] = f32x4{0.f, 0.f, 0.f, 0.f};

    // prologue: buf0 <- tile0 (4 units); buf1 <- tile1 partial (mh0, nh1)
    STG_A(0, 0, 0); STG_A(0, 1, 0); STG_B(0, 0, 0); STG_B(0, 1, 0);
    STG_A(1, 0, 1); STG_B(1, 1, 1);
    asm volatile("s_waitcnt vmcnt(4)" ::: "memory");   // buf0 complete
    BARSYNC;

#pragma unroll 1
    for (int i = 0; i < 8; ++i) {
        const int t1 = 2 * i + 1;
        const int t2 = (2 * i + 2) & 15;   // dummy re-read on last iter (safe)
        const int t3 = (2 * i + 3) & 15;
        // ph1 (buf0, mh0, nh0)
        LOADA(0, 0); LOADB(bfA, 0, 0); STG_B(t1, 0, 1);
        BARSYNC; WAITLGKM; MFMA16(0, 0, bfA); BARSYNC;
        // ph2 (buf0, mh0, nh1)
        LOADB(bfB, 0, 1); STG_A(t1, 1, 1);
        BARSYNC; WAITLGKM; MFMA16(0, 1, bfB); BARSYNC;
        // ph3 (buf0, mh1, nh1)
        LOADA(0, 1); STG_A(t2, 0, 0);
        BARSYNC; WAITLGKM; MFMA16(1, 1, bfB); BARSYNC;
        // ph4 (buf0, mh1, nh0) reuses bfA + drain: buf1 <- t1 complete
        STG_B(t2, 1, 0);
        BARSYNC; MFMA16(1, 0, bfA);
        asm volatile("s_waitcnt vmcnt(4)" ::: "memory"); BARSYNC;
        // ph5 (buf1, mh0, nh0)
        LOADA(1, 0); LOADB(bfA, 1, 0); STG_A(t2, 1, 0);
        BARSYNC; WAITLGKM; MFMA16(0, 0, bfA); BARSYNC;
        // ph6 (buf1, mh0, nh1)
        LOADB(bfB, 1, 1); STG_B(t2, 0, 0);
        BARSYNC; WAITLGKM; MFMA16(0, 1, bfB); BARSYNC;
        // ph7 (buf1, mh1, nh1)
        LOADA(1, 1); STG_A(t3, 0, 1);
        BARSYNC; WAITLGKM; MFMA16(1, 1, bfB); BARSYNC;
        // ph8 (buf1, mh1, nh0) reuses bfA + drain: buf0 <- t2 complete
        STG_B(t3, 1, 1);
        BARSYNC; MFMA16(1, 0, bfA);
        asm volatile("s_waitcnt vmcnt(4)" ::: "memory"); BARSYNC;
    }
    asm volatile("s_waitcnt vmcnt(0)" ::: "memory");   // drain dummy stages

#undef STG_A
#undef STG_B
#undef LOADA
#undef LOADB
#undef MFMA16
}

// ===================== 256x384 8-phase GEMM core =====================
// LDS 160KB ushort map: A[buf][256][64] at buf*16384 (32768 total);
//                       B[buf][384][64] at 32768 + buf*24576 (49152 total).
// Waves 2M x 4N: per-wave 128x96, acc[8][6]. Phase MFMA = 4x3x2 = 24.
// A units (16KB, 2 loads/thr): rows {0,128}+mh*64..+63.
// B units (24KB, 3 loads/thr): rows {0,96,192,288}+nh*48..+47.
// Same window schedule as 256-core; loads/phase 3,2,2,3,2,3,2,3 ->
// steady in-flight 15, WAITV(5) at ph4/ph8.
__device__ __forceinline__ void gemm384_core(
    const unsigned short* __restrict__ Ab,   // + gm0*ld
    const unsigned short* __restrict__ Bb,   // + gn0*ld
    const long ld, unsigned short* lds, f32x4 acc[8][6])
{
    const int tid  = threadIdx.x;
    const int w    = tid >> 6;
    const int lane = tid & 63;

    const int r  = lane >> 3;
    const int s  = lane & 7;
    const int cg = (s ^ r) * 8;

    const int fr    = lane & 15;
    const int quad  = lane >> 4;
    const int sw    = fr & 7;
    const int arow0 = (w >> 2) * 128;
    const int brow0 = (w & 3) * 96;

#define STG_A3(t, mh, buf) do {                                             \
    const int rb_ = (w >> 2) * 128 + (mh) * 64 + (w & 3) * 16;              \
    const unsigned short* g_ = Ab + (long)(rb_ + r) * ld + (long)(t) * 64 + cg; \
    unsigned short* d_ = lds + (buf) * 16384 + rb_ * 64;                    \
    GLDS16(g_, d_); GLDS16(g_ + 8 * ld, d_ + 512); } while (0)
#define STG_B3(t, nh, buf) do {                                             \
    _Pragma("unroll") for (int q_ = 0; q_ < 3; q_++) {                      \
        const int u_ = w * 3 + q_;                                          \
        const int row0_ = (u_ & 3) * 96 + (nh) * 48 + (u_ >> 2) * 8;        \
        const unsigned short* g_ = Bb + (long)(row0_ + r) * ld + (long)(t) * 64 + cg; \
        unsigned short* d_ = lds + 32768 + (buf) * 24576 + row0_ * 64;      \
        GLDS16(g_, d_); } } while (0)

    bf16x8 af[4][2], bfA[3][2], bfB[3][2];
#define LOADA3(buf, mh) do {                                                \
    _Pragma("unroll") for (int ks_ = 0; ks_ < 2; ks_++)                     \
    _Pragma("unroll") for (int i_ = 0; i_ < 4; i_++)                        \
        af[i_][ks_] = *(const bf16x8*)&lds[(buf) * 16384 +                  \
            (arow0 + (mh) * 64 + i_ * 16 + fr) * 64 +                       \
            ((ks_ * 4 + quad) ^ sw) * 8]; } while (0)
#define LOADB3(BF, buf, nh) do {                                            \
    _Pragma("unroll") for (int ks_ = 0; ks_ < 2; ks_++)                     \
    _Pragma("unroll") for (int j_ = 0; j_ < 3; j_++)                        \
        BF[j_][ks_] = *(const bf16x8*)&lds[32768 + (buf) * 24576 +          \
            (brow0 + (nh) * 48 + j_ * 16 + fr) * 64 +                       \
            ((ks_ * 4 + quad) ^ sw) * 8]; } while (0)

#define MFMA24(mh, nh, BF) do {                                             \
    __builtin_amdgcn_s_setprio(1);                                          \
    _Pragma("unroll") for (int ks_ = 0; ks_ < 2; ks_++)                     \
    _Pragma("unroll") for (int i_ = 0; i_ < 4; i_++)                        \
    _Pragma("unroll") for (int j_ = 0; j_ < 3; j_++)                        \
        acc[(mh) * 4 + i_][(nh) * 3 + j_] =                                 \
            __builtin_amdgcn_mfma_f32_16x16x32_bf16(                        \
                af[i_][ks_], BF[j_][ks_],                                   \
                acc[(mh) * 4 + i_][(nh) * 3 + j_], 0, 0, 0);                \
    __builtin_amdgcn_s_setprio(0); } while (0)

#pragma unroll
    for (int i = 0; i < 8; i++)
#pragma unroll
        for (int j = 0; j < 6; j++) acc[i][j] = f32x4{0.f, 0.f, 0.f, 0.f};

    // prologue: buf0 <- tile0 (10 loads); buf1 <- tile1 partial (A-mh0, B-nh1)
    STG_A3(0, 0, 0); STG_A3(0, 1, 0); STG_B3(0, 0, 0); STG_B3(0, 1, 0);
    STG_A3(1, 0, 1); STG_B3(1, 1, 1);
    asm volatile("s_waitcnt vmcnt(5)" ::: "memory");   // buf0 complete
    BARSYNC;

#pragma unroll 1
    for (int i = 0; i < 8; ++i) {
        const int t1 = 2 * i + 1;
        const int t2 = (2 * i + 2) & 15;
        const int t3 = (2 * i + 3) & 15;
        // ph1 (buf0, mh0, nh0)
        LOADA3(0, 0); LOADB3(bfA, 0, 0); STG_B3(t1, 0, 1);
        BARSYNC; WAITLGKM; MFMA24(0, 0, bfA); BARSYNC;
        // ph2 (buf0, mh0, nh1)
        LOADB3(bfB, 0, 1); STG_A3(t1, 1, 1);
        BARSYNC; WAITLGKM; MFMA24(0, 1, bfB); BARSYNC;
        // ph3 (buf0, mh1, nh1)
        LOADA3(0, 1); STG_A3(t2, 0, 0);
        BARSYNC; WAITLGKM; MFMA24(1, 1, bfB); BARSYNC;
        // ph4 (buf0, mh1, nh0) reuses bfA + drain buf1(t1) prefix
        STG_B3(t2, 1, 0);
        BARSYNC; MFMA24(1, 0, bfA);
        asm volatile("s_waitcnt vmcnt(5)" ::: "memory"); BARSYNC;
        // ph5 (buf1, mh0, nh0)
        LOADA3(1, 0); LOADB3(bfA, 1, 0); STG_A3(t2, 1, 0);
        BARSYNC; WAITLGKM; MFMA24(0, 0, bfA); BARSYNC;
        // ph6 (buf1, mh0, nh1)
        LOADB3(bfB, 1, 1); STG_B3(t2, 0, 0);
        BARSYNC; WAITLGKM; MFMA24(0, 1, bfB); BARSYNC;
        // ph7 (buf1, mh1, nh1)
        LOADA3(1, 1); STG_A3(t3, 0, 1);
        BARSYNC; WAITLGKM; MFMA24(1, 1, bfB); BARSYNC;
        // ph8 (buf1, mh1, nh0) reuses bfA + drain buf0(t2)
        STG_B3(t3, 1, 1);
        BARSYNC; MFMA24(1, 0, bfA);
        asm volatile("s_waitcnt vmcnt(5)" ::: "memory"); BARSYNC;
    }
    asm volatile("s_waitcnt vmcnt(0)" ::: "memory");   // drain dummy stages

#undef STG_A3
#undef STG_B3
#undef LOADA3
#undef LOADB3
#undef MFMA24
}

// ---------------- QKV fused GEMM (256x384 8-phase, grid 256 exact) --------
// A = xb [8192x1024]; B = Wqkvt [3072x1024] (Wq^T|Wk^T|Wv^T).
// col < 2048 -> QK[m*2048 + col] (bf16); col >= 2048 -> Vt[(col-2048)*8192+m]
// XCD swizzle: 256 blocks, each XCD owns 4 M-panels x all 8 N-tiles.
__global__ __launch_bounds__(512, 2) void gemm_qkv384(
    const unsigned short* __restrict__ A, const unsigned short* __restrict__ B,
    unsigned short* __restrict__ QK, unsigned short* __restrict__ Vt)
{
    __shared__ unsigned short lds[81920];   // 160 KB
    const int orig = blockIdx.x;
    const int xcd  = orig & 7;
    const int pos  = orig >> 3;           // 0..31
    const long gm0 = (long)(xcd * 4 + (pos & 3)) * 256;
    const long gn0 = (long)(pos >> 2) * 384;

    f32x4 acc[8][6];
    gemm384_core(A + gm0 * 1024, B + gn0 * 1024, 1024, lds, acc);

    const int tid = threadIdx.x;
    const int w = tid >> 6, lane = tid & 63;
    const int fr = lane & 15, quad = lane >> 4;
    const int wm = (w >> 2) * 128, wn = (w & 3) * 96;

#pragma unroll
    for (int mi = 0; mi < 8; mi++) {
        const long rb = gm0 + wm + (mi >> 2) * 64 + (mi & 3) * 16 + quad * 4;
#pragma unroll
        for (int nj = 0; nj < 6; nj++) {
            const long cb = gn0 + wn + nj * 16 + fr;
            if (cb < 2048) {
#pragma unroll
                for (int rr = 0; rr < 4; rr++)
                    QK[(rb + rr) * 2048L + cb] = f2bf(acc[mi][nj][rr]);
            } else {
                const long ce = cb - 2048;
                ushort4 o;
                o.x = f2bf(acc[mi][nj][0]);
                o.y = f2bf(acc[mi][nj][1]);
                o.z = f2bf(acc[mi][nj][2]);
                o.w = f2bf(acc[mi][nj][3]);
                *(ushort4*)&Vt[ce * 8192L + rb] = o;
            }
        }
    }
}

// ------------- scores GEMM (256^2 8-phase): P'[j,i] = exp((K_j.Q_i)/32) -----
// 256 blocks = exact single round. XCD swizzle: each XCD owns half a batch.
__global__ __launch_bounds__(512, 2) void gemm_scores256(
    const unsigned short* __restrict__ QKb, unsigned short* __restrict__ P,
    float* __restrict__ l)
{
    __shared__ unsigned short lds[65536];
    const int orig = blockIdx.x;
    const int xcd  = orig & 7;
    const int pos  = orig >> 3;           // 0..31
    const int bz   = xcd >> 1;
    const long gm0 = (long)((xcd & 1) * 4 + (pos >> 3)) * 256;  // j (K rows)
    const long gn0 = (long)(pos & 7) * 256;                     // i (Q rows)

    const unsigned short* Ab = QKb + (long)bz * 2048 * 2048 + 1024 + gm0 * 2048;
    const unsigned short* Bb = QKb + (long)bz * 2048 * 2048 + gn0 * 2048;

    f32x4 acc[8][4];
    gemm256_core(Ab, Bb, 2048, lds, acc);

    const int tid = threadIdx.x;
    const int w = tid >> 6, lane = tid & 63;
    const int fr = lane & 15, quad = lane >> 4;
    const int wm = (w >> 2) * 128, wn = (w & 3) * 64;

    unsigned short* Pb = P + (long)bz * 2048 * 2048;
    float* lb = l + (long)bz * 2048;
    const float scale = 1.0f / 32.0f;
#pragma unroll
    for (int mi = 0; mi < 8; mi++) {
        const long rb = gm0 + wm + (mi >> 2) * 64 + (mi & 3) * 16 + quad * 4;
        float rs[4] = {0.f, 0.f, 0.f, 0.f};
#pragma unroll
        for (int n = 0; n < 4; n++) {
            const long cb = gn0 + wn + n * 16 + fr;
#pragma unroll
            for (int rr = 0; rr < 4; rr++) {
                float e = __expf(acc[mi][n][rr] * scale);
                rs[rr] += e;
                Pb[(rb + rr) * 2048L + cb] = f2bf(e);
            }
        }
#pragma unroll
        for (int rr = 0; rr < 4; rr++) {
#pragma unroll
            for (int m = 8; m > 0; m >>= 1) rs[rr] += __shfl_xor(rs[rr], m, 16);
        }
        if (fr == 0) {
#pragma unroll
            for (int rr = 0; rr < 4; rr++)
                atomicAdd(&lb[rb + rr], rs[rr]);
        }
    }
}

// ---------------- PV GEMM: 128x128 tiles, fp32 out, /l[row] ----------------
// out_b[j,e] = (sum_i P'_b[j,i] * Vt[e, b*2048+i]) / l[b][j]
// grid (8 e-tiles, 16 j-tiles, 4 batches). Same-e blocks are 8 apart in
// dispatch order -> same XCD -> Vt tile stays L2-resident.
__global__ __launch_bounds__(256) void gemm_pv(
    const unsigned short* __restrict__ P, const unsigned short* __restrict__ Vt,
    const float* __restrict__ l, float* __restrict__ out)
{
    __shared__ unsigned short As[128 * 64];
    __shared__ unsigned short Bs[128 * 64];

    const int tid  = threadIdx.x;
    const int wave = tid >> 6;
    const int lane = tid & 63;
    const int bz   = blockIdx.z;
    const long gm0 = (long)blockIdx.y * 128;   // j
    const long gn0 = (long)blockIdx.x * 128;   // e

    const unsigned short* Ab = P + (long)bz * 2048 * 2048;
    const unsigned short* Bb = Vt + (long)bz * 2048;

    const int r = lane >> 3;
    const int s = lane & 7;
    const int cg = (s ^ r) * 8;
    const unsigned short* ap = Ab + (gm0 + wave * 32 + r) * 2048L + cg;
    const unsigned short* bp = Bb + (gn0 + wave * 32 + r) * 8192L + cg;
    unsigned short* asl = &As[wave * 2048];
    unsigned short* bsl = &Bs[wave * 2048];

    const int wm   = (wave & 1) * 64;
    const int wn   = (wave >> 1) * 64;
    const int fr   = lane & 15;
    const int quad = lane >> 4;
    const int sw   = fr & 7;

    f32x4 acc[4][4];
#pragma unroll
    for (int i = 0; i < 4; i++)
#pragma unroll
        for (int j = 0; j < 4; j++) acc[i][j] = f32x4{0.f, 0.f, 0.f, 0.f};

    for (int k0 = 0; k0 < 2048; k0 += 64) {
        GLDS16(ap, asl);
        GLDS16(ap + 8 * 2048L, asl + 512);
        GLDS16(ap + 16 * 2048L, asl + 1024);
        GLDS16(ap + 24 * 2048L, asl + 1536);
        GLDS16(bp, bsl);
        GLDS16(bp + 8 * 8192L, bsl + 512);
        GLDS16(bp + 16 * 8192L, bsl + 1024);
        GLDS16(bp + 24 * 8192L, bsl + 1536);
        ap += 64;
        bp += 64;
        __syncthreads();

#pragma unroll
        for (int t = 0; t < 2; t++) {
            const int qs = ((t * 4 + quad) ^ sw) * 8;
            bf16x8 af[4], bf[4];
#pragma unroll
            for (int i = 0; i < 4; i++)
                af[i] = *(const bf16x8*)&As[(wm + i * 16 + fr) * 64 + qs];
#pragma unroll
            for (int j = 0; j < 4; j++)
                bf[j] = *(const bf16x8*)&Bs[(wn + j * 16 + fr) * 64 + qs];
#pragma unroll
            for (int i = 0; i < 4; i++)
#pragma unroll
                for (int j = 0; j < 4; j++)
                    acc[i][j] = __builtin_amdgcn_mfma_f32_16x16x32_bf16(
                        af[i], bf[j], acc[i][j], 0, 0, 0);
        }
        __syncthreads();
    }

    float* Ob = out + (long)bz * 2048 * 1024;
    const float* lb = l + (long)bz * 2048;
    const long crow0 = gm0 + wm + quad * 4;
#pragma unroll
    for (int i = 0; i < 4; i++) {
        const long rb = crow0 + i * 16;
        float inv[4];
#pragma unroll
        for (int rr = 0; rr < 4; rr++) inv[rr] = 1.0f / lb[rb + rr];
#pragma unroll
        for (int j = 0; j < 4; j++) {
            const long cb = gn0 + wn + j * 16 + fr;
#pragma unroll
            for (int rr = 0; rr < 4; rr++)
                Ob[(rb + rr) * 1024L + cb] = acc[i][j][rr] * inv[rr];
        }
    }
}

// Fused prep: [0,8192) convert x; [8192,8192+3072) transpose weights;
// block 11264 zeroes l (8192 floats).
__global__ __launch_bounds__(256) void prep(
    const float* __restrict__ x,
    const float* __restrict__ Wq, const float* __restrict__ Wk,
    const float* __restrict__ Wv,
    unsigned short* __restrict__ xb, unsigned short* __restrict__ Wqkvt,
    float* __restrict__ l)
{
    __shared__ float t[32][33];
    const int b = blockIdx.x;
    const int tid = threadIdx.x;
    if (b < 8192) {
        int i = b * 256 + tid;
        float4 v = ((const float4*)x)[i];
        ushort4 o;
        o.x = f2bf(v.x); o.y = f2bf(v.y); o.z = f2bf(v.z); o.w = f2bf(v.w);
        ((ushort4*)xb)[i] = o;
        return;
    }
    if (b == 8192 + 3072) {
        float4 z = {0.f, 0.f, 0.f, 0.f};
#pragma unroll
        for (int i = 0; i < 8; i++)
            ((float4*)l)[tid * 8 + i] = z;
        return;
    }
    int tix = b - 8192;
    const int w = tix >> 10;
    tix &= 1023;
    const float* W = (w == 0) ? Wq : (w == 1) ? Wk : Wv;
    unsigned short* Wt = Wqkvt + (long)w * 1024 * 1024;
    const int bx = (tix & 31) * 32;
    const int by = (tix >> 5) * 32;
    const int tx = tid & 31;
    const int ty = (tid >> 5) * 4;
#pragma unroll
    for (int j = 0; j < 4; j++)
        t[ty + j][tx] = W[(long)(by + ty + j) * 1024 + bx + tx];
    __syncthreads();
#pragma unroll
    for (int j = 0; j < 4; j++)
        Wt[(long)(bx + ty + j) * 1024 + by + tx] = f2bf(t[tx][ty + j]);
}

extern "C" void kernel_launch(void* const* d_in, const int* in_sizes, int n_in,
                              void* d_out, int out_size, void* d_ws,
                              size_t ws_size, hipStream_t stream)
{
    const float* x  = (const float*)d_in[0];
    const float* Wq = (const float*)d_in[1];
    const float* Wk = (const float*)d_in[2];
    const float* Wv = (const float*)d_in[3];
    float* out = (float*)d_out;

    const long M1 = 1024 * 1024;
    unsigned short* u     = (unsigned short*)d_ws;
    unsigned short* xb    = u;                  // 8M
    unsigned short* Wqkvt = u + 8 * M1;         // 3M
    unsigned short* QKb   = Wqkvt + 3 * M1;     // 16M [8192 x 2048]
    unsigned short* Vtb   = QKb + 16 * M1;      // 8M  [1024 x 8192]
    unsigned short* Pb    = Vtb + 8 * M1;       // 16M [4 x 2048 x 2048]
    float* l              = (float*)(Pb + 16 * M1);  // 8192 f32

    prep<<<dim3(8192 + 3072 + 1), dim3(256), 0, stream>>>(x, Wq, Wk, Wv, xb, Wqkvt, l);

    // QKV fused: [8192x1024] @ [3072x1024]^T, 256x384 tiles, 256 blocks exact
    gemm_qkv384<<<dim3(256), dim3(512), 0, stream>>>(xb, Wqkvt, QKb, Vtb);

    // P'[j,i] = exp((K_j.Q_i)/32) bf16, + row sums l, 256^2 8-phase
    gemm_scores256<<<dim3(256), dim3(512), 0, stream>>>(QKb, Pb, l);

    // out = (P' @ V) / l  (128x128 tiles)
    gemm_pv<<<dim3(8, 16, 4), dim3(256), 0, stream>>>(Pb, Vtb, l, out);
}

// Round 6
// 227.437 us; speedup vs baseline: 1.7111x; 1.7111x over previous
//
#include <hip/hip_runtime.h>
#include <math.h>

// SelfAttentionLayer B=4, N=2048, D=E=1024, fp32 in/out.
// out[b,j,e] = sum_i softmax_i(q_i . k_j / 32) * v[b,i,e]
// R13 (2nd resubmit; R4/R5 benches never ran - broker timeouts):
//      revert R12's 256x384 qkv (L2 thrash cliff: FETCH 329MB = zero-reuse
//      bound, 237us). qkv back to R11 grid/swizzle (43MB, 71.8us proven) on
//      the R12 core (bf-reg caching, passed via scores). NEW: pv ported to
//      the same verified 8-phase schedule, 256(j)x128(e) tiles, grid
//      8x8x4 = 256 blocks exact single round; vmcnt(3) at ph4/ph8.
//
// ws (ushort): xb[8M] Wqkvt[3M] QKb[16M] Vtb[8M] Pb[16M] l[8192 f32].

typedef __bf16 bf16x8 __attribute__((ext_vector_type(8)));
typedef float f32x4 __attribute__((ext_vector_type(4)));

static __device__ __forceinline__ unsigned short f2bf(float f) {
    unsigned u = __float_as_uint(f);
    u += 0x7fff + ((u >> 16) & 1);   // round-to-nearest-even
    return (unsigned short)(u >> 16);
}

#define GLDS16(gptr, lptr)                                                            \
    __builtin_amdgcn_global_load_lds(                                                 \
        (const __attribute__((address_space(1))) void*)(gptr),                        \
        (__attribute__((address_space(3))) void*)(lptr), 16, 0, 0)

#define BARSYNC  __builtin_amdgcn_s_barrier()
#define WAITLGKM do { asm volatile("s_waitcnt lgkmcnt(0)" ::: "memory");    \
                      __builtin_amdgcn_sched_barrier(0); } while (0)

// ===================== 256x256 8-phase GEMM core =====================
// (R11/R12 structure, proven: conflicts 0, passed refcheck twice.)
// LDS 128KiB ushort map: A[buf][256][64] at buf*16384; B at 32768+buf*16384.
// Stage units: A(mh) rows {0,128}+mh*64..+63 ; B(nh) rows {0,64,128,192}+nh*32..+31
// Schedule (iter i: buf0=tile 2i, buf1=2i+1; t1=2i+1,t2=2i+2,t3=2i+3):
//  ph1(0,0,0):ldA0+ldB->bfA, STG_B(t1,0,b1)  ph5(1,0,0): same, STG_A(t2,1,b0)
//  ph2(0,0,1):ldB->bfB,      STG_A(t1,1,b1)  ph6(1,0,1): ldB->bfB, STG_B(t2,0,b0)
//  ph3(0,1,1):ldA1,          STG_A(t2,0,b0)  ph7(1,1,1): ldA1,     STG_A(t3,0,b1)
//  ph4(0,1,0):(no reads),    STG_B(t2,1,b0)  ph8(1,1,0): (none),   STG_B(t3,1,b1)
//  WAITV(4) after ph4/ph8 MFMA. Every stage >=1 close-barrier after last read.
__device__ __forceinline__ void gemm256_core(
    const unsigned short* __restrict__ Ab,   // + gm0*ld
    const unsigned short* __restrict__ Bb,   // + gn0*ld
    const long ld, unsigned short* lds, f32x4 acc[8][4])
{
    const int tid  = threadIdx.x;
    const int w    = tid >> 6;
    const int lane = tid & 63;

    const int r  = lane >> 3;
    const int s  = lane & 7;
    const int cg = (s ^ r) * 8;

    const int fr    = lane & 15;
    const int quad  = lane >> 4;
    const int sw    = fr & 7;
    const int arow0 = (w >> 2) * 128;
    const int brow0 = (w & 3) * 64;

#define STG_A(t, mh, buf) do {                                              \
    const int rb_ = (w >> 2) * 128 + (mh) * 64 + (w & 3) * 16;              \
    const unsigned short* g_ = Ab + (long)(rb_ + r) * ld + (long)(t) * 64 + cg; \
    unsigned short* d_ = lds + (buf) * 16384 + rb_ * 64;                    \
    GLDS16(g_, d_); GLDS16(g_ + 8 * ld, d_ + 512); } while (0)
#define STG_B(t, nh, buf) do {                                              \
    const int rb_ = (w >> 1) * 64 + (nh) * 32 + (w & 1) * 16;               \
    const unsigned short* g_ = Bb + (long)(rb_ + r) * ld + (long)(t) * 64 + cg; \
    unsigned short* d_ = lds + 32768 + (buf) * 16384 + rb_ * 64;            \
    GLDS16(g_, d_); GLDS16(g_ + 8 * ld, d_ + 512); } while (0)

    bf16x8 af[4][2], bfA[2][2], bfB[2][2];
#define LOADA(buf, mh) do {                                                 \
    _Pragma("unroll") for (int ks_ = 0; ks_ < 2; ks_++)                     \
    _Pragma("unroll") for (int i_ = 0; i_ < 4; i_++)                        \
        af[i_][ks_] = *(const bf16x8*)&lds[(buf) * 16384 +                  \
            (arow0 + (mh) * 64 + i_ * 16 + fr) * 64 +                       \
            ((ks_ * 4 + quad) ^ sw) * 8]; } while (0)
#define LOADB(BF, buf, nh) do {                                             \
    _Pragma("unroll") for (int ks_ = 0; ks_ < 2; ks_++)                     \
    _Pragma("unroll") for (int j_ = 0; j_ < 2; j_++)                        \
        BF[j_][ks_] = *(const bf16x8*)&lds[32768 + (buf) * 16384 +          \
            (brow0 + (nh) * 32 + j_ * 16 + fr) * 64 +                       \
            ((ks_ * 4 + quad) ^ sw) * 8]; } while (0)

#define MFMA16(mh, nh, BF) do {                                             \
    __builtin_amdgcn_s_setprio(1);                                          \
    _Pragma("unroll") for (int ks_ = 0; ks_ < 2; ks_++)                     \
    _Pragma("unroll") for (int i_ = 0; i_ < 4; i_++)                        \
    _Pragma("unroll") for (int j_ = 0; j_ < 2; j_++)                        \
        acc[(mh) * 4 + i_][(nh) * 2 + j_] =                                 \
            __builtin_amdgcn_mfma_f32_16x16x32_bf16(                        \
                af[i_][ks_], BF[j_][ks_],                                   \
                acc[(mh) * 4 + i_][(nh) * 2 + j_], 0, 0, 0);                \
    __builtin_amdgcn_s_setprio(0); } while (0)

#pragma unroll
    for (int i = 0; i < 8; i++)
#pragma unroll
        for (int j = 0; j < 4; j++) acc[i][j] = f32x4{0.f, 0.f, 0.f, 0.f};

    // prologue: buf0 <- tile0 (4 units); buf1 <- tile1 partial (mh0, nh1)
    STG_A(0, 0, 0); STG_A(0, 1, 0); STG_B(0, 0, 0); STG_B(0, 1, 0);
    STG_A(1, 0, 1); STG_B(1, 1, 1);
    asm volatile("s_waitcnt vmcnt(4)" ::: "memory");   // buf0 complete
    BARSYNC;

#pragma unroll 1
    for (int i = 0; i < 8; ++i) {
        const int t1 = 2 * i + 1;
        const int t2 = (2 * i + 2) & 15;   // dummy re-read on last iter (safe)
        const int t3 = (2 * i + 3) & 15;
        // ph1 (buf0, mh0, nh0)
        LOADA(0, 0); LOADB(bfA, 0, 0); STG_B(t1, 0, 1);
        BARSYNC; WAITLGKM; MFMA16(0, 0, bfA); BARSYNC;
        // ph2 (buf0, mh0, nh1)
        LOADB(bfB, 0, 1); STG_A(t1, 1, 1);
        BARSYNC; WAITLGKM; MFMA16(0, 1, bfB); BARSYNC;
        // ph3 (buf0, mh1, nh1)
        LOADA(0, 1); STG_A(t2, 0, 0);
        BARSYNC; WAITLGKM; MFMA16(1, 1, bfB); BARSYNC;
        // ph4 (buf0, mh1, nh0) reuses bfA + drain: buf1 <- t1 complete
        STG_B(t2, 1, 0);
        BARSYNC; MFMA16(1, 0, bfA);
        asm volatile("s_waitcnt vmcnt(4)" ::: "memory"); BARSYNC;
        // ph5 (buf1, mh0, nh0)
        LOADA(1, 0); LOADB(bfA, 1, 0); STG_A(t2, 1, 0);
        BARSYNC; WAITLGKM; MFMA16(0, 0, bfA); BARSYNC;
        // ph6 (buf1, mh0, nh1)
        LOADB(bfB, 1, 1); STG_B(t2, 0, 0);
        BARSYNC; WAITLGKM; MFMA16(0, 1, bfB); BARSYNC;
        // ph7 (buf1, mh1, nh1)
        LOADA(1, 1); STG_A(t3, 0, 1);
        BARSYNC; WAITLGKM; MFMA16(1, 1, bfB); BARSYNC;
        // ph8 (buf1, mh1, nh0) reuses bfA + drain: buf0 <- t2 complete
        STG_B(t3, 1, 1);
        BARSYNC; MFMA16(1, 0, bfA);
        asm volatile("s_waitcnt vmcnt(4)" ::: "memory"); BARSYNC;
    }
    asm volatile("s_waitcnt vmcnt(0)" ::: "memory");   // drain dummy stages

#undef STG_A
#undef STG_B
#undef LOADA
#undef LOADB
#undef MFMA16
}

// ===================== 256x128 8-phase PV core =====================
// A = P rows (lda 2048), B = Vt rows (ldb 8192). K = 2048 (32 tiles).
// LDS 96KB ushort: A[buf][256][64] at buf*16384; B[buf][128][64] at
// 32768 + buf*8192. Waves 2Mx4N: per-wave 128x32, acc[8][2].
// A units as 256-core; B unit(nh): rows {0,32,64,96}+nh*16..+15 (8KB,
// 1 GLDS16/thread). Same window schedule; loads/phase 1,2,2,1,2,1,2,1
// -> steady in-flight 9, WAITV(3) at ph4/ph8. All 8 region windows
// verified: stage lands >=1 barrier after last read, drains >=2 phases
// before first read.
__device__ __forceinline__ void pv256_core(
    const unsigned short* __restrict__ Ab,   // P + bz*4M + gm0*2048
    const unsigned short* __restrict__ Bb,   // Vt + gn0*8192 + bz*2048
    unsigned short* lds, f32x4 acc[8][2])
{
    const int tid  = threadIdx.x;
    const int w    = tid >> 6;
    const int lane = tid & 63;

    const int r  = lane >> 3;
    const int s  = lane & 7;
    const int cg = (s ^ r) * 8;

    const int fr    = lane & 15;
    const int quad  = lane >> 4;
    const int sw    = fr & 7;
    const int arow0 = (w >> 2) * 128;
    const int brow0 = (w & 3) * 32;

#define STG_PA(t, mh, buf) do {                                             \
    const int rb_ = (w >> 2) * 128 + (mh) * 64 + (w & 3) * 16;              \
    const unsigned short* g_ = Ab + (long)(rb_ + r) * 2048 + (long)(t) * 64 + cg; \
    unsigned short* d_ = lds + (buf) * 16384 + rb_ * 64;                    \
    GLDS16(g_, d_); GLDS16(g_ + 8 * 2048, d_ + 512); } while (0)
#define STG_PB(t, nh, buf) do {                                             \
    const int rb_ = (w & 3) * 32 + (nh) * 16 + (w >> 2) * 8;                \
    const unsigned short* g_ = Bb + (long)(rb_ + r) * 8192 + (long)(t) * 64 + cg; \
    unsigned short* d_ = lds + 32768 + (buf) * 8192 + rb_ * 64;             \
    GLDS16(g_, d_); } while (0)

    bf16x8 af[4][2], bfA[2], bfB[2];
#define LOADPA(buf, mh) do {                                                \
    _Pragma("unroll") for (int ks_ = 0; ks_ < 2; ks_++)                     \
    _Pragma("unroll") for (int i_ = 0; i_ < 4; i_++)                        \
        af[i_][ks_] = *(const bf16x8*)&lds[(buf) * 16384 +                  \
            (arow0 + (mh) * 64 + i_ * 16 + fr) * 64 +                       \
            ((ks_ * 4 + quad) ^ sw) * 8]; } while (0)
#define LOADPB(BF, buf, nh) do {                                            \
    _Pragma("unroll") for (int ks_ = 0; ks_ < 2; ks_++)                     \
        BF[ks_] = *(const bf16x8*)&lds[32768 + (buf) * 8192 +               \
            (brow0 + (nh) * 16 + fr) * 64 +                                 \
            ((ks_ * 4 + quad) ^ sw) * 8]; } while (0)

#define MFMA8(mh, nh, BF) do {                                              \
    __builtin_amdgcn_s_setprio(1);                                          \
    _Pragma("unroll") for (int ks_ = 0; ks_ < 2; ks_++)                     \
    _Pragma("unroll") for (int i_ = 0; i_ < 4; i_++)                        \
        acc[(mh) * 4 + i_][nh] = __builtin_amdgcn_mfma_f32_16x16x32_bf16(   \
            af[i_][ks_], BF[ks_], acc[(mh) * 4 + i_][nh], 0, 0, 0);         \
    __builtin_amdgcn_s_setprio(0); } while (0)

#pragma unroll
    for (int i = 0; i < 8; i++)
#pragma unroll
        for (int j = 0; j < 2; j++) acc[i][j] = f32x4{0.f, 0.f, 0.f, 0.f};

    // prologue: buf0 <- tile0 (6 loads); buf1 <- tile1 partial (A-mh0 2, B-nh1 1)
    STG_PA(0, 0, 0); STG_PA(0, 1, 0); STG_PB(0, 0, 0); STG_PB(0, 1, 0);
    STG_PA(1, 0, 1); STG_PB(1, 1, 1);
    asm volatile("s_waitcnt vmcnt(3)" ::: "memory");   // buf0 complete
    BARSYNC;

#pragma unroll 1
    for (int i = 0; i < 16; ++i) {
        const int t1 = 2 * i + 1;
        const int t2 = (2 * i + 2) & 31;   // dummy re-read on last iter (safe)
        const int t3 = (2 * i + 3) & 31;
        // ph1 (buf0, mh0, nh0)
        LOADPA(0, 0); LOADPB(bfA, 0, 0); STG_PB(t1, 0, 1);
        BARSYNC; WAITLGKM; MFMA8(0, 0, bfA); BARSYNC;
        // ph2 (buf0, mh0, nh1)
        LOADPB(bfB, 0, 1); STG_PA(t1, 1, 1);
        BARSYNC; WAITLGKM; MFMA8(0, 1, bfB); BARSYNC;
        // ph3 (buf0, mh1, nh1)
        LOADPA(0, 1); STG_PA(t2, 0, 0);
        BARSYNC; WAITLGKM; MFMA8(1, 1, bfB); BARSYNC;
        // ph4 (buf0, mh1, nh0) reuses bfA + drain: buf1 <- t1 complete
        STG_PB(t2, 1, 0);
        BARSYNC; MFMA8(1, 0, bfA);
        asm volatile("s_waitcnt vmcnt(3)" ::: "memory"); BARSYNC;
        // ph5 (buf1, mh0, nh0)
        LOADPA(1, 0); LOADPB(bfA, 1, 0); STG_PA(t2, 1, 0);
        BARSYNC; WAITLGKM; MFMA8(0, 0, bfA); BARSYNC;
        // ph6 (buf1, mh0, nh1)
        LOADPB(bfB, 1, 1); STG_PB(t2, 0, 0);
        BARSYNC; WAITLGKM; MFMA8(0, 1, bfB); BARSYNC;
        // ph7 (buf1, mh1, nh1)
        LOADPA(1, 1); STG_PA(t3, 0, 1);
        BARSYNC; WAITLGKM; MFMA8(1, 1, bfB); BARSYNC;
        // ph8 (buf1, mh1, nh0) reuses bfA + drain: buf0 <- t2 complete
        STG_PB(t3, 1, 1);
        BARSYNC; MFMA8(1, 0, bfA);
        asm volatile("s_waitcnt vmcnt(3)" ::: "memory"); BARSYNC;
    }
    asm volatile("s_waitcnt vmcnt(0)" ::: "memory");   // drain dummy stages

#undef STG_PA
#undef STG_PB
#undef LOADPA
#undef LOADPB
#undef MFMA8
}

// ---------------- QKV fused GEMM (256^2 8-phase) ----------------
// A = xb [8192x1024]; B = Wqkvt [3072x1024] (Wq^T|Wk^T|Wv^T).
// n < 2048 -> QK[m*2048 + n] (bf16); n >= 2048 -> Vt[(n-2048)*8192 + m]
// XCD swizzle: 384 blocks, each XCD owns 4 M-panels x all N (R11-proven,
// FETCH 43MB).
__global__ __launch_bounds__(512, 2) void gemm_qkv256(
    const unsigned short* __restrict__ A, const unsigned short* __restrict__ B,
    unsigned short* __restrict__ QK, unsigned short* __restrict__ Vt)
{
    __shared__ unsigned short lds[65536];
    const int orig = blockIdx.x;
    const int xcd  = orig & 7;
    const int pos  = orig >> 3;           // 0..47
    const long gm0 = (long)(xcd * 4 + (pos & 3)) * 256;
    const long gn0 = (long)(pos >> 2) * 256;

    f32x4 acc[8][4];
    gemm256_core(A + gm0 * 1024, B + gn0 * 1024, 1024, lds, acc);

    const int tid = threadIdx.x;
    const int w = tid >> 6, lane = tid & 63;
    const int fr = lane & 15, quad = lane >> 4;
    const int wm = (w >> 2) * 128, wn = (w & 3) * 64;

    if (gn0 < 2048) {
#pragma unroll
        for (int mi = 0; mi < 8; mi++) {
            const long rb = gm0 + wm + (mi >> 2) * 64 + (mi & 3) * 16 + quad * 4;
#pragma unroll
            for (int n = 0; n < 4; n++) {
                const long cb = gn0 + wn + n * 16 + fr;
#pragma unroll
                for (int rr = 0; rr < 4; rr++)
                    QK[(rb + rr) * 2048L + cb] = f2bf(acc[mi][n][rr]);
            }
        }
    } else {
#pragma unroll
        for (int mi = 0; mi < 8; mi++) {
            const long rb = gm0 + wm + (mi >> 2) * 64 + (mi & 3) * 16 + quad * 4;
#pragma unroll
            for (int n = 0; n < 4; n++) {
                const long ce = gn0 - 2048 + wn + n * 16 + fr;
                ushort4 o;
                o.x = f2bf(acc[mi][n][0]);
                o.y = f2bf(acc[mi][n][1]);
                o.z = f2bf(acc[mi][n][2]);
                o.w = f2bf(acc[mi][n][3]);
                *(ushort4*)&Vt[ce * 8192L + rb] = o;
            }
        }
    }
}

// ------------- scores GEMM (256^2 8-phase): P'[j,i] = exp((K_j.Q_i)/32) -----
// 256 blocks = exact single round. XCD swizzle: each XCD owns half a batch.
__global__ __launch_bounds__(512, 2) void gemm_scores256(
    const unsigned short* __restrict__ QKb, unsigned short* __restrict__ P,
    float* __restrict__ l)
{
    __shared__ unsigned short lds[65536];
    const int orig = blockIdx.x;
    const int xcd  = orig & 7;
    const int pos  = orig >> 3;           // 0..31
    const int bz   = xcd >> 1;
    const long gm0 = (long)((xcd & 1) * 4 + (pos >> 3)) * 256;  // j (K rows)
    const long gn0 = (long)(pos & 7) * 256;                     // i (Q rows)

    const unsigned short* Ab = QKb + (long)bz * 2048 * 2048 + 1024 + gm0 * 2048;
    const unsigned short* Bb = QKb + (long)bz * 2048 * 2048 + gn0 * 2048;

    f32x4 acc[8][4];
    gemm256_core(Ab, Bb, 2048, lds, acc);

    const int tid = threadIdx.x;
    const int w = tid >> 6, lane = tid & 63;
    const int fr = lane & 15, quad = lane >> 4;
    const int wm = (w >> 2) * 128, wn = (w & 3) * 64;

    unsigned short* Pb = P + (long)bz * 2048 * 2048;
    float* lb = l + (long)bz * 2048;
    const float scale = 1.0f / 32.0f;
#pragma unroll
    for (int mi = 0; mi < 8; mi++) {
        const long rb = gm0 + wm + (mi >> 2) * 64 + (mi & 3) * 16 + quad * 4;
        float rs[4] = {0.f, 0.f, 0.f, 0.f};
#pragma unroll
        for (int n = 0; n < 4; n++) {
            const long cb = gn0 + wn + n * 16 + fr;
#pragma unroll
            for (int rr = 0; rr < 4; rr++) {
                float e = __expf(acc[mi][n][rr] * scale);
                rs[rr] += e;
                Pb[(rb + rr) * 2048L + cb] = f2bf(e);
            }
        }
#pragma unroll
        for (int rr = 0; rr < 4; rr++) {
#pragma unroll
            for (int m = 8; m > 0; m >>= 1) rs[rr] += __shfl_xor(rs[rr], m, 16);
        }
        if (fr == 0) {
#pragma unroll
            for (int rr = 0; rr < 4; rr++)
                atomicAdd(&lb[rb + rr], rs[rr]);
        }
    }
}

// ---------------- PV GEMM (256x128 8-phase): out = (P' @ V)/l ------------
// out_b[j,e] = (sum_i P'_b[j,i] * Vt[e, b*2048+i]) / l[b][j]
// Grid 256 = exact single round. XCD swizzle: bz = xcd>>1, each XCD owns
// 4 j-tiles x 8 e-tiles of one batch half.
__global__ __launch_bounds__(512, 2) void gemm_pv256(
    const unsigned short* __restrict__ P, const unsigned short* __restrict__ Vt,
    const float* __restrict__ l, float* __restrict__ out)
{
    __shared__ unsigned short lds[49152];   // 96 KB
    const int orig = blockIdx.x;
    const int xcd  = orig & 7;
    const int pos  = orig >> 3;           // 0..31
    const int bz   = xcd >> 1;
    const long gm0 = (long)((xcd & 1) * 4 + (pos >> 3)) * 256;  // j
    const long gn0 = (long)(pos & 7) * 128;                     // e

    const unsigned short* Ab = P + (long)bz * 2048 * 2048 + gm0 * 2048;
    const unsigned short* Bb = Vt + gn0 * 8192 + (long)bz * 2048;

    f32x4 acc[8][2];
    pv256_core(Ab, Bb, lds, acc);

    const int tid = threadIdx.x;
    const int w = tid >> 6, lane = tid & 63;
    const int fr = lane & 15, quad = lane >> 4;
    const int wm = (w >> 2) * 128, wn = (w & 3) * 32;

    float* Ob = out + (long)bz * 2048 * 1024;
    const float* lb = l + (long)bz * 2048;
#pragma unroll
    for (int mi = 0; mi < 8; mi++) {
        const long rb = gm0 + wm + (mi >> 2) * 64 + (mi & 3) * 16 + quad * 4;
        float inv[4];
#pragma unroll
        for (int rr = 0; rr < 4; rr++) inv[rr] = 1.0f / lb[rb + rr];
#pragma unroll
        for (int nj = 0; nj < 2; nj++) {
            const long cb = gn0 + wn + nj * 16 + fr;
#pragma unroll
            for (int rr = 0; rr < 4; rr++)
                Ob[(rb + rr) * 1024L + cb] = acc[mi][nj][rr] * inv[rr];
        }
    }
}

// Fused prep: [0,8192) convert x; [8192,8192+3072) transpose weights;
// block 11264 zeroes l (8192 floats).
__global__ __launch_bounds__(256) void prep(
    const float* __restrict__ x,
    const float* __restrict__ Wq, const float* __restrict__ Wk,
    const float* __restrict__ Wv,
    unsigned short* __restrict__ xb, unsigned short* __restrict__ Wqkvt,
    float* __restrict__ l)
{
    __shared__ float t[32][33];
    const int b = blockIdx.x;
    const int tid = threadIdx.x;
    if (b < 8192) {
        int i = b * 256 + tid;
        float4 v = ((const float4*)x)[i];
        ushort4 o;
        o.x = f2bf(v.x); o.y = f2bf(v.y); o.z = f2bf(v.z); o.w = f2bf(v.w);
        ((ushort4*)xb)[i] = o;
        return;
    }
    if (b == 8192 + 3072) {
        float4 z = {0.f, 0.f, 0.f, 0.f};
#pragma unroll
        for (int i = 0; i < 8; i++)
            ((float4*)l)[tid * 8 + i] = z;
        return;
    }
    int tix = b - 8192;
    const int w = tix >> 10;
    tix &= 1023;
    const float* W = (w == 0) ? Wq : (w == 1) ? Wk : Wv;
    unsigned short* Wt = Wqkvt + (long)w * 1024 * 1024;
    const int bx = (tix & 31) * 32;
    const int by = (tix >> 5) * 32;
    const int tx = tid & 31;
    const int ty = (tid >> 5) * 4;
#pragma unroll
    for (int j = 0; j < 4; j++)
        t[ty + j][tx] = W[(long)(by + ty + j) * 1024 + bx + tx];
    __syncthreads();
#pragma unroll
    for (int j = 0; j < 4; j++)
        Wt[(long)(bx + ty + j) * 1024 + by + tx] = f2bf(t[tx][ty + j]);
}

extern "C" void kernel_launch(void* const* d_in, const int* in_sizes, int n_in,
                              void* d_out, int out_size, void* d_ws,
                              size_t ws_size, hipStream_t stream)
{
    const float* x  = (const float*)d_in[0];
    const float* Wq = (const float*)d_in[1];
    const float* Wk = (const float*)d_in[2];
    const float* Wv = (const float*)d_in[3];
    float* out = (float*)d_out;

    const long M1 = 1024 * 1024;
    unsigned short* u     = (unsigned short*)d_ws;
    unsigned short* xb    = u;                  // 8M
    unsigned short* Wqkvt = u + 8 * M1;         // 3M
    unsigned short* QKb   = Wqkvt + 3 * M1;     // 16M [8192 x 2048]
    unsigned short* Vtb   = QKb + 16 * M1;      // 8M  [1024 x 8192]
    unsigned short* Pb    = Vtb + 8 * M1;       // 16M [4 x 2048 x 2048]
    float* l              = (float*)(Pb + 16 * M1);  // 8192 f32

    prep<<<dim3(8192 + 3072 + 1), dim3(256), 0, stream>>>(x, Wq, Wk, Wv, xb, Wqkvt, l);

    // QKV fused: [8192x1024] @ [3072x1024]^T, 256^2 8-phase, XCD-swizzled
    gemm_qkv256<<<dim3(384), dim3(512), 0, stream>>>(xb, Wqkvt, QKb, Vtb);

    // P'[j,i] = exp((K_j.Q_i)/32) bf16, + row sums l, 256^2 8-phase
    gemm_scores256<<<dim3(256), dim3(512), 0, stream>>>(QKb, Pb, l);

    // out = (P' @ V) / l, 256x128 8-phase, 256 blocks exact
    gemm_pv256<<<dim3(256), dim3(512), 0, stream>>>(Pb, Vtb, l, out);
}

// Round 10
// 220.983 us; speedup vs baseline: 1.7611x; 1.0292x over previous
//
#include <hip/hip_runtime.h>
#include <math.h>

// SelfAttentionLayer B=4, N=2048, D=E=1024, fp32 in/out.
// out[b,j,e] = sum_i softmax_i(q_i . k_j / 32) * v[b,i,e]
// R14 (4th resubmit; R7/R8/R9 benches never ran - broker timeouts):
//      split qkv (384 blocks = 1.5 rounds, 23us tail) into two EXACT-round
//      kernels: gemm_qk256 (N=2048, 256 blocks, proven 256-core) and
//      gemm_v128 (N=1024, 128x256 tiles, 256 blocks, new half-M core with
//      vmcnt(3) at ph4/ph8). scores/pv unchanged from R13 (passed).
//
// ws (ushort): xb[8M] Wqkvt[3M] QKb[16M] Vtb[8M] Pb[16M] l[8192 f32].

typedef __bf16 bf16x8 __attribute__((ext_vector_type(8)));
typedef float f32x4 __attribute__((ext_vector_type(4)));

static __device__ __forceinline__ unsigned short f2bf(float f) {
    unsigned u = __float_as_uint(f);
    u += 0x7fff + ((u >> 16) & 1);   // round-to-nearest-even
    return (unsigned short)(u >> 16);
}

#define GLDS16(gptr, lptr)                                                            \
    __builtin_amdgcn_global_load_lds(                                                 \
        (const __attribute__((address_space(1))) void*)(gptr),                        \
        (__attribute__((address_space(3))) void*)(lptr), 16, 0, 0)

#define BARSYNC  __builtin_amdgcn_s_barrier()
#define WAITLGKM do { asm volatile("s_waitcnt lgkmcnt(0)" ::: "memory");    \
                      __builtin_amdgcn_sched_barrier(0); } while (0)

// ===================== 256x256 8-phase GEMM core =====================
// (R11/R12/R13 structure, proven: conflicts 0, passed refcheck 3x.)
// LDS 128KiB ushort map: A[buf][256][64] at buf*16384; B at 32768+buf*16384.
// Stage units: A(mh) rows {0,128}+mh*64..+63 ; B(nh) rows {0,64,128,192}+nh*32..+31
// Schedule (iter i: buf0=tile 2i, buf1=2i+1; t1=2i+1,t2=2i+2,t3=2i+3):
//  ph1(0,0,0):ldA0+ldB->bfA, STG_B(t1,0,b1)  ph5(1,0,0): same, STG_A(t2,1,b0)
//  ph2(0,0,1):ldB->bfB,      STG_A(t1,1,b1)  ph6(1,0,1): ldB->bfB, STG_B(t2,0,b0)
//  ph3(0,1,1):ldA1,          STG_A(t2,0,b0)  ph7(1,1,1): ldA1,     STG_A(t3,0,b1)
//  ph4(0,1,0):(no reads),    STG_B(t2,1,b0)  ph8(1,1,0): (none),   STG_B(t3,1,b1)
//  WAITV(4) after ph4/ph8 MFMA. Every stage >=1 close-barrier after last read.
__device__ __forceinline__ void gemm256_core(
    const unsigned short* __restrict__ Ab,   // + gm0*ld
    const unsigned short* __restrict__ Bb,   // + gn0*ld
    const long ld, unsigned short* lds, f32x4 acc[8][4])
{
    const int tid  = threadIdx.x;
    const int w    = tid >> 6;
    const int lane = tid & 63;

    const int r  = lane >> 3;
    const int s  = lane & 7;
    const int cg = (s ^ r) * 8;

    const int fr    = lane & 15;
    const int quad  = lane >> 4;
    const int sw    = fr & 7;
    const int arow0 = (w >> 2) * 128;
    const int brow0 = (w & 3) * 64;

#define STG_A(t, mh, buf) do {                                              \
    const int rb_ = (w >> 2) * 128 + (mh) * 64 + (w & 3) * 16;              \
    const unsigned short* g_ = Ab + (long)(rb_ + r) * ld + (long)(t) * 64 + cg; \
    unsigned short* d_ = lds + (buf) * 16384 + rb_ * 64;                    \
    GLDS16(g_, d_); GLDS16(g_ + 8 * ld, d_ + 512); } while (0)
#define STG_B(t, nh, buf) do {                                              \
    const int rb_ = (w >> 1) * 64 + (nh) * 32 + (w & 1) * 16;               \
    const unsigned short* g_ = Bb + (long)(rb_ + r) * ld + (long)(t) * 64 + cg; \
    unsigned short* d_ = lds + 32768 + (buf) * 16384 + rb_ * 64;            \
    GLDS16(g_, d_); GLDS16(g_ + 8 * ld, d_ + 512); } while (0)

    bf16x8 af[4][2], bfA[2][2], bfB[2][2];
#define LOADA(buf, mh) do {                                                 \
    _Pragma("unroll") for (int ks_ = 0; ks_ < 2; ks_++)                     \
    _Pragma("unroll") for (int i_ = 0; i_ < 4; i_++)                        \
        af[i_][ks_] = *(const bf16x8*)&lds[(buf) * 16384 +                  \
            (arow0 + (mh) * 64 + i_ * 16 + fr) * 64 +                       \
            ((ks_ * 4 + quad) ^ sw) * 8]; } while (0)
#define LOADB(BF, buf, nh) do {                                             \
    _Pragma("unroll") for (int ks_ = 0; ks_ < 2; ks_++)                     \
    _Pragma("unroll") for (int j_ = 0; j_ < 2; j_++)                        \
        BF[j_][ks_] = *(const bf16x8*)&lds[32768 + (buf) * 16384 +          \
            (brow0 + (nh) * 32 + j_ * 16 + fr) * 64 +                       \
            ((ks_ * 4 + quad) ^ sw) * 8]; } while (0)

#define MFMA16(mh, nh, BF) do {                                             \
    __builtin_amdgcn_s_setprio(1);                                          \
    _Pragma("unroll") for (int ks_ = 0; ks_ < 2; ks_++)                     \
    _Pragma("unroll") for (int i_ = 0; i_ < 4; i_++)                        \
    _Pragma("unroll") for (int j_ = 0; j_ < 2; j_++)                        \
        acc[(mh) * 4 + i_][(nh) * 2 + j_] =                                 \
            __builtin_amdgcn_mfma_f32_16x16x32_bf16(                        \
                af[i_][ks_], BF[j_][ks_],                                   \
                acc[(mh) * 4 + i_][(nh) * 2 + j_], 0, 0, 0);                \
    __builtin_amdgcn_s_setprio(0); } while (0)

#pragma unroll
    for (int i = 0; i < 8; i++)
#pragma unroll
        for (int j = 0; j < 4; j++) acc[i][j] = f32x4{0.f, 0.f, 0.f, 0.f};

    // prologue: buf0 <- tile0 (4 units); buf1 <- tile1 partial (mh0, nh1)
    STG_A(0, 0, 0); STG_A(0, 1, 0); STG_B(0, 0, 0); STG_B(0, 1, 0);
    STG_A(1, 0, 1); STG_B(1, 1, 1);
    asm volatile("s_waitcnt vmcnt(4)" ::: "memory");   // buf0 complete
    BARSYNC;

#pragma unroll 1
    for (int i = 0; i < 8; ++i) {
        const int t1 = 2 * i + 1;
        const int t2 = (2 * i + 2) & 15;   // dummy re-read on last iter (safe)
        const int t3 = (2 * i + 3) & 15;
        // ph1 (buf0, mh0, nh0)
        LOADA(0, 0); LOADB(bfA, 0, 0); STG_B(t1, 0, 1);
        BARSYNC; WAITLGKM; MFMA16(0, 0, bfA); BARSYNC;
        // ph2 (buf0, mh0, nh1)
        LOADB(bfB, 0, 1); STG_A(t1, 1, 1);
        BARSYNC; WAITLGKM; MFMA16(0, 1, bfB); BARSYNC;
        // ph3 (buf0, mh1, nh1)
        LOADA(0, 1); STG_A(t2, 0, 0);
        BARSYNC; WAITLGKM; MFMA16(1, 1, bfB); BARSYNC;
        // ph4 (buf0, mh1, nh0) reuses bfA + drain: buf1 <- t1 complete
        STG_B(t2, 1, 0);
        BARSYNC; MFMA16(1, 0, bfA);
        asm volatile("s_waitcnt vmcnt(4)" ::: "memory"); BARSYNC;
        // ph5 (buf1, mh0, nh0)
        LOADA(1, 0); LOADB(bfA, 1, 0); STG_A(t2, 1, 0);
        BARSYNC; WAITLGKM; MFMA16(0, 0, bfA); BARSYNC;
        // ph6 (buf1, mh0, nh1)
        LOADB(bfB, 1, 1); STG_B(t2, 0, 0);
        BARSYNC; WAITLGKM; MFMA16(0, 1, bfB); BARSYNC;
        // ph7 (buf1, mh1, nh1)
        LOADA(1, 1); STG_A(t3, 0, 1);
        BARSYNC; WAITLGKM; MFMA16(1, 1, bfB); BARSYNC;
        // ph8 (buf1, mh1, nh0) reuses bfA + drain: buf0 <- t2 complete
        STG_B(t3, 1, 1);
        BARSYNC; MFMA16(1, 0, bfA);
        asm volatile("s_waitcnt vmcnt(4)" ::: "memory"); BARSYNC;
    }
    asm volatile("s_waitcnt vmcnt(0)" ::: "memory");   // drain dummy stages

#undef STG_A
#undef STG_B
#undef LOADA
#undef LOADB
#undef MFMA16
}

// ===================== 128x256 8-phase V core =====================
// A = xb (128 m-rows, ld 1024), B = Wvt (256 e-rows, ld 1024). K = 1024.
// LDS 96KB ushort: A[buf][128][64] at buf*8192; B[buf][256][64] at
// 16384 + buf*16384. Waves 2Mx4N: per-wave 64x64, acc[4][4].
// A unit(mh): rows {0,64}+mh*32..+31 (8KB, 1 GLDS/thread,
//   rb_=(w>>2)*64+mh*32+(w&3)*8). B unit(nh): as 256-core (2 GLDS/thread).
// Same window schedule; per-iter loads 12; ph3+ph4 = 1+2 = 3 ->
// WAITV(3) at ph4/ph8. Prologue 9 loads, drain to 3.
__device__ __forceinline__ void gemm_v128_core(
    const unsigned short* __restrict__ Ab,   // xb + gm0*1024
    const unsigned short* __restrict__ Bb,   // Wvt + gn0*1024
    unsigned short* lds, f32x4 acc[4][4])
{
    const int tid  = threadIdx.x;
    const int w    = tid >> 6;
    const int lane = tid & 63;

    const int r  = lane >> 3;
    const int s  = lane & 7;
    const int cg = (s ^ r) * 8;

    const int fr    = lane & 15;
    const int quad  = lane >> 4;
    const int sw    = fr & 7;
    const int arow0 = (w >> 2) * 64;
    const int brow0 = (w & 3) * 64;

#define STG_VA(t, mh, buf) do {                                             \
    const int rb_ = (w >> 2) * 64 + (mh) * 32 + (w & 3) * 8;                \
    const unsigned short* g_ = Ab + (long)(rb_ + r) * 1024 + (long)(t) * 64 + cg; \
    unsigned short* d_ = lds + (buf) * 8192 + rb_ * 64;                     \
    GLDS16(g_, d_); } while (0)
#define STG_VB(t, nh, buf) do {                                             \
    const int rb_ = (w >> 1) * 64 + (nh) * 32 + (w & 1) * 16;               \
    const unsigned short* g_ = Bb + (long)(rb_ + r) * 1024 + (long)(t) * 64 + cg; \
    unsigned short* d_ = lds + 16384 + (buf) * 16384 + rb_ * 64;            \
    GLDS16(g_, d_); GLDS16(g_ + 8 * 1024, d_ + 512); } while (0)

    bf16x8 af[2][2], bfA[2][2], bfB[2][2];
#define LOADVA(buf, mh) do {                                                \
    _Pragma("unroll") for (int ks_ = 0; ks_ < 2; ks_++)                     \
    _Pragma("unroll") for (int i_ = 0; i_ < 2; i_++)                        \
        af[i_][ks_] = *(const bf16x8*)&lds[(buf) * 8192 +                   \
            (arow0 + (mh) * 32 + i_ * 16 + fr) * 64 +                       \
            ((ks_ * 4 + quad) ^ sw) * 8]; } while (0)
#define LOADVB(BF, buf, nh) do {                                            \
    _Pragma("unroll") for (int ks_ = 0; ks_ < 2; ks_++)                     \
    _Pragma("unroll") for (int j_ = 0; j_ < 2; j_++)                        \
        BF[j_][ks_] = *(const bf16x8*)&lds[16384 + (buf) * 16384 +          \
            (brow0 + (nh) * 32 + j_ * 16 + fr) * 64 +                       \
            ((ks_ * 4 + quad) ^ sw) * 8]; } while (0)

#define MFMA_V(mh, nh, BF) do {                                             \
    __builtin_amdgcn_s_setprio(1);                                          \
    _Pragma("unroll") for (int ks_ = 0; ks_ < 2; ks_++)                     \
    _Pragma("unroll") for (int i_ = 0; i_ < 2; i_++)                        \
    _Pragma("unroll") for (int j_ = 0; j_ < 2; j_++)                        \
        acc[(mh) * 2 + i_][(nh) * 2 + j_] =                                 \
            __builtin_amdgcn_mfma_f32_16x16x32_bf16(                        \
                af[i_][ks_], BF[j_][ks_],                                   \
                acc[(mh) * 2 + i_][(nh) * 2 + j_], 0, 0, 0);                \
    __builtin_amdgcn_s_setprio(0); } while (0)

#pragma unroll
    for (int i = 0; i < 4; i++)
#pragma unroll
        for (int j = 0; j < 4; j++) acc[i][j] = f32x4{0.f, 0.f, 0.f, 0.f};

    // prologue: buf0 <- tile0 (6 loads); buf1 <- tile1 partial (A-mh0 1, B-nh1 2)
    STG_VA(0, 0, 0); STG_VA(0, 1, 0); STG_VB(0, 0, 0); STG_VB(0, 1, 0);
    STG_VA(1, 0, 1); STG_VB(1, 1, 1);
    asm volatile("s_waitcnt vmcnt(3)" ::: "memory");   // buf0 complete
    BARSYNC;

#pragma unroll 1
    for (int i = 0; i < 8; ++i) {
        const int t1 = 2 * i + 1;
        const int t2 = (2 * i + 2) & 15;   // dummy re-read on last iter (safe)
        const int t3 = (2 * i + 3) & 15;
        // ph1 (buf0, mh0, nh0)
        LOADVA(0, 0); LOADVB(bfA, 0, 0); STG_VB(t1, 0, 1);
        BARSYNC; WAITLGKM; MFMA_V(0, 0, bfA); BARSYNC;
        // ph2 (buf0, mh0, nh1)
        LOADVB(bfB, 0, 1); STG_VA(t1, 1, 1);
        BARSYNC; WAITLGKM; MFMA_V(0, 1, bfB); BARSYNC;
        // ph3 (buf0, mh1, nh1)
        LOADVA(0, 1); STG_VA(t2, 0, 0);
        BARSYNC; WAITLGKM; MFMA_V(1, 1, bfB); BARSYNC;
        // ph4 (buf0, mh1, nh0) reuses bfA + drain: buf1 <- t1 complete
        STG_VB(t2, 1, 0);
        BARSYNC; MFMA_V(1, 0, bfA);
        asm volatile("s_waitcnt vmcnt(3)" ::: "memory"); BARSYNC;
        // ph5 (buf1, mh0, nh0)
        LOADVA(1, 0); LOADVB(bfA, 1, 0); STG_VA(t2, 1, 0);
        BARSYNC; WAITLGKM; MFMA_V(0, 0, bfA); BARSYNC;
        // ph6 (buf1, mh0, nh1)
        LOADVB(bfB, 1, 1); STG_VB(t2, 0, 0);
        BARSYNC; WAITLGKM; MFMA_V(0, 1, bfB); BARSYNC;
        // ph7 (buf1, mh1, nh1)
        LOADVA(1, 1); STG_VA(t3, 0, 1);
        BARSYNC; WAITLGKM; MFMA_V(1, 1, bfB); BARSYNC;
        // ph8 (buf1, mh1, nh0) reuses bfA + drain: buf0 <- t2 complete
        STG_VB(t3, 1, 1);
        BARSYNC; MFMA_V(1, 0, bfA);
        asm volatile("s_waitcnt vmcnt(3)" ::: "memory"); BARSYNC;
    }
    asm volatile("s_waitcnt vmcnt(0)" ::: "memory");   // drain dummy stages

#undef STG_VA
#undef STG_VB
#undef LOADVA
#undef LOADVB
#undef MFMA_V
}

// ===================== 256x128 8-phase PV core =====================
// (R13 structure, passed refcheck.) A = P rows (lda 2048), B = Vt rows
// (ldb 8192). K = 2048 (32 tiles). LDS 96KB. WAITV(3) at ph4/ph8.
__device__ __forceinline__ void pv256_core(
    const unsigned short* __restrict__ Ab,   // P + bz*4M + gm0*2048
    const unsigned short* __restrict__ Bb,   // Vt + gn0*8192 + bz*2048
    unsigned short* lds, f32x4 acc[8][2])
{
    const int tid  = threadIdx.x;
    const int w    = tid >> 6;
    const int lane = tid & 63;

    const int r  = lane >> 3;
    const int s  = lane & 7;
    const int cg = (s ^ r) * 8;

    const int fr    = lane & 15;
    const int quad  = lane >> 4;
    const int sw    = fr & 7;
    const int arow0 = (w >> 2) * 128;
    const int brow0 = (w & 3) * 32;

#define STG_PA(t, mh, buf) do {                                             \
    const int rb_ = (w >> 2) * 128 + (mh) * 64 + (w & 3) * 16;              \
    const unsigned short* g_ = Ab + (long)(rb_ + r) * 2048 + (long)(t) * 64 + cg; \
    unsigned short* d_ = lds + (buf) * 16384 + rb_ * 64;                    \
    GLDS16(g_, d_); GLDS16(g_ + 8 * 2048, d_ + 512); } while (0)
#define STG_PB(t, nh, buf) do {                                             \
    const int rb_ = (w & 3) * 32 + (nh) * 16 + (w >> 2) * 8;                \
    const unsigned short* g_ = Bb + (long)(rb_ + r) * 8192 + (long)(t) * 64 + cg; \
    unsigned short* d_ = lds + 32768 + (buf) * 8192 + rb_ * 64;             \
    GLDS16(g_, d_); } while (0)

    bf16x8 af[4][2], bfA[2], bfB[2];
#define LOADPA(buf, mh) do {                                                \
    _Pragma("unroll") for (int ks_ = 0; ks_ < 2; ks_++)                     \
    _Pragma("unroll") for (int i_ = 0; i_ < 4; i_++)                        \
        af[i_][ks_] = *(const bf16x8*)&lds[(buf) * 16384 +                  \
            (arow0 + (mh) * 64 + i_ * 16 + fr) * 64 +                       \
            ((ks_ * 4 + quad) ^ sw) * 8]; } while (0)
#define LOADPB(BF, buf, nh) do {                                            \
    _Pragma("unroll") for (int ks_ = 0; ks_ < 2; ks_++)                     \
        BF[ks_] = *(const bf16x8*)&lds[32768 + (buf) * 8192 +               \
            (brow0 + (nh) * 16 + fr) * 64 +                                 \
            ((ks_ * 4 + quad) ^ sw) * 8]; } while (0)

#define MFMA8(mh, nh, BF) do {                                              \
    __builtin_amdgcn_s_setprio(1);                                          \
    _Pragma("unroll") for (int ks_ = 0; ks_ < 2; ks_++)                     \
    _Pragma("unroll") for (int i_ = 0; i_ < 4; i_++)                        \
        acc[(mh) * 4 + i_][nh] = __builtin_amdgcn_mfma_f32_16x16x32_bf16(   \
            af[i_][ks_], BF[ks_], acc[(mh) * 4 + i_][nh], 0, 0, 0);         \
    __builtin_amdgcn_s_setprio(0); } while (0)

#pragma unroll
    for (int i = 0; i < 8; i++)
#pragma unroll
        for (int j = 0; j < 2; j++) acc[i][j] = f32x4{0.f, 0.f, 0.f, 0.f};

    // prologue: buf0 <- tile0 (6 loads); buf1 <- tile1 partial (A-mh0 2, B-nh1 1)
    STG_PA(0, 0, 0); STG_PA(0, 1, 0); STG_PB(0, 0, 0); STG_PB(0, 1, 0);
    STG_PA(1, 0, 1); STG_PB(1, 1, 1);
    asm volatile("s_waitcnt vmcnt(3)" ::: "memory");   // buf0 complete
    BARSYNC;

#pragma unroll 1
    for (int i = 0; i < 16; ++i) {
        const int t1 = 2 * i + 1;
        const int t2 = (2 * i + 2) & 31;   // dummy re-read on last iter (safe)
        const int t3 = (2 * i + 3) & 31;
        // ph1 (buf0, mh0, nh0)
        LOADPA(0, 0); LOADPB(bfA, 0, 0); STG_PB(t1, 0, 1);
        BARSYNC; WAITLGKM; MFMA8(0, 0, bfA); BARSYNC;
        // ph2 (buf0, mh0, nh1)
        LOADPB(bfB, 0, 1); STG_PA(t1, 1, 1);
        BARSYNC; WAITLGKM; MFMA8(0, 1, bfB); BARSYNC;
        // ph3 (buf0, mh1, nh1)
        LOADPA(0, 1); STG_PA(t2, 0, 0);
        BARSYNC; WAITLGKM; MFMA8(1, 1, bfB); BARSYNC;
        // ph4 (buf0, mh1, nh0) reuses bfA + drain: buf1 <- t1 complete
        STG_PB(t2, 1, 0);
        BARSYNC; MFMA8(1, 0, bfA);
        asm volatile("s_waitcnt vmcnt(3)" ::: "memory"); BARSYNC;
        // ph5 (buf1, mh0, nh0)
        LOADPA(1, 0); LOADPB(bfA, 1, 0); STG_PA(t2, 1, 0);
        BARSYNC; WAITLGKM; MFMA8(0, 0, bfA); BARSYNC;
        // ph6 (buf1, mh0, nh1)
        LOADPB(bfB, 1, 1); STG_PB(t2, 0, 0);
        BARSYNC; WAITLGKM; MFMA8(0, 1, bfB); BARSYNC;
        // ph7 (buf1, mh1, nh1)
        LOADPA(1, 1); STG_PA(t3, 0, 1);
        BARSYNC; WAITLGKM; MFMA8(1, 1, bfB); BARSYNC;
        // ph8 (buf1, mh1, nh0) reuses bfA + drain: buf0 <- t2 complete
        STG_PB(t3, 1, 1);
        BARSYNC; MFMA8(1, 0, bfA);
        asm volatile("s_waitcnt vmcnt(3)" ::: "memory"); BARSYNC;
    }
    asm volatile("s_waitcnt vmcnt(0)" ::: "memory");   // drain dummy stages

#undef STG_PA
#undef STG_PB
#undef LOADPA
#undef LOADPB
#undef MFMA8
}

// ---------------- Q/K GEMM (256^2 8-phase, 256 blocks exact) --------------
// A = xb [8192x1024]; B = Wqkvt [2048x1024] (Wq^T|Wk^T part).
// Out: QK[m*2048 + n] bf16. XCD swizzle: each XCD owns 4 M-panels x all N.
__global__ __launch_bounds__(512, 2) void gemm_qk256(
    const unsigned short* __restrict__ A, const unsigned short* __restrict__ B,
    unsigned short* __restrict__ QK)
{
    __shared__ unsigned short lds[65536];
    const int orig = blockIdx.x;
    const int xcd  = orig & 7;
    const int pos  = orig >> 3;           // 0..31
    const long gm0 = (long)(xcd * 4 + (pos & 3)) * 256;
    const long gn0 = (long)(pos >> 2) * 256;

    f32x4 acc[8][4];
    gemm256_core(A + gm0 * 1024, B + gn0 * 1024, 1024, lds, acc);

    const int tid = threadIdx.x;
    const int w = tid >> 6, lane = tid & 63;
    const int fr = lane & 15, quad = lane >> 4;
    const int wm = (w >> 2) * 128, wn = (w & 3) * 64;

#pragma unroll
    for (int mi = 0; mi < 8; mi++) {
        const long rb = gm0 + wm + (mi >> 2) * 64 + (mi & 3) * 16 + quad * 4;
#pragma unroll
        for (int n = 0; n < 4; n++) {
            const long cb = gn0 + wn + n * 16 + fr;
#pragma unroll
            for (int rr = 0; rr < 4; rr++)
                QK[(rb + rr) * 2048L + cb] = f2bf(acc[mi][n][rr]);
        }
    }
}

// ---------------- V GEMM (128x256 8-phase, 256 blocks exact) ---------------
// A = xb [8192x1024]; B = Wvt [1024x1024]. Out: Vt[e*8192 + m] bf16.
// XCD swizzle: each XCD owns 8 M-panels (128 rows) x all 4 e-tiles (Wv 2MB
// + A 2MB = 4MB, L2-fit).
__global__ __launch_bounds__(512, 2) void gemm_v128(
    const unsigned short* __restrict__ A, const unsigned short* __restrict__ B,
    unsigned short* __restrict__ Vt)
{
    __shared__ unsigned short lds[49152];   // 96 KB
    const int orig = blockIdx.x;
    const int xcd  = orig & 7;
    const int pos  = orig >> 3;           // 0..31
    const long gm0 = (long)(xcd * 8 + (pos & 7)) * 128;
    const long gn0 = (long)(pos >> 3) * 256;

    f32x4 acc[4][4];
    gemm_v128_core(A + gm0 * 1024, B + gn0 * 1024, lds, acc);

    const int tid = threadIdx.x;
    const int w = tid >> 6, lane = tid & 63;
    const int fr = lane & 15, quad = lane >> 4;
    const int wm = (w >> 2) * 64, wn = (w & 3) * 64;

#pragma unroll
    for (int ai = 0; ai < 4; ai++) {
        const long rb = gm0 + wm + ai * 16 + quad * 4;
#pragma unroll
        for (int aj = 0; aj < 4; aj++) {
            const long ce = gn0 + wn + aj * 16 + fr;
            ushort4 o;
            o.x = f2bf(acc[ai][aj][0]);
            o.y = f2bf(acc[ai][aj][1]);
            o.z = f2bf(acc[ai][aj][2]);
            o.w = f2bf(acc[ai][aj][3]);
            *(ushort4*)&Vt[ce * 8192L + rb] = o;
        }
    }
}

// ------------- scores GEMM (256^2 8-phase): P'[j,i] = exp((K_j.Q_i)/32) -----
// 256 blocks = exact single round. XCD swizzle: each XCD owns half a batch.
__global__ __launch_bounds__(512, 2) void gemm_scores256(
    const unsigned short* __restrict__ QKb, unsigned short* __restrict__ P,
    float* __restrict__ l)
{
    __shared__ unsigned short lds[65536];
    const int orig = blockIdx.x;
    const int xcd  = orig & 7;
    const int pos  = orig >> 3;           // 0..31
    const int bz   = xcd >> 1;
    const long gm0 = (long)((xcd & 1) * 4 + (pos >> 3)) * 256;  // j (K rows)
    const long gn0 = (long)(pos & 7) * 256;                     // i (Q rows)

    const unsigned short* Ab = QKb + (long)bz * 2048 * 2048 + 1024 + gm0 * 2048;
    const unsigned short* Bb = QKb + (long)bz * 2048 * 2048 + gn0 * 2048;

    f32x4 acc[8][4];
    gemm256_core(Ab, Bb, 2048, lds, acc);

    const int tid = threadIdx.x;
    const int w = tid >> 6, lane = tid & 63;
    const int fr = lane & 15, quad = lane >> 4;
    const int wm = (w >> 2) * 128, wn = (w & 3) * 64;

    unsigned short* Pb = P + (long)bz * 2048 * 2048;
    float* lb = l + (long)bz * 2048;
    const float scale = 1.0f / 32.0f;
#pragma unroll
    for (int mi = 0; mi < 8; mi++) {
        const long rb = gm0 + wm + (mi >> 2) * 64 + (mi & 3) * 16 + quad * 4;
        float rs[4] = {0.f, 0.f, 0.f, 0.f};
#pragma unroll
        for (int n = 0; n < 4; n++) {
            const long cb = gn0 + wn + n * 16 + fr;
#pragma unroll
            for (int rr = 0; rr < 4; rr++) {
                float e = __expf(acc[mi][n][rr] * scale);
                rs[rr] += e;
                Pb[(rb + rr) * 2048L + cb] = f2bf(e);
            }
        }
#pragma unroll
        for (int rr = 0; rr < 4; rr++) {
#pragma unroll
            for (int m = 8; m > 0; m >>= 1) rs[rr] += __shfl_xor(rs[rr], m, 16);
        }
        if (fr == 0) {
#pragma unroll
            for (int rr = 0; rr < 4; rr++)
                atomicAdd(&lb[rb + rr], rs[rr]);
        }
    }
}

// ---------------- PV GEMM (256x128 8-phase): out = (P' @ V)/l ------------
// out_b[j,e] = (sum_i P'_b[j,i] * Vt[e, b*2048+i]) / l[b][j]
// Grid 256 = exact single round. XCD swizzle: bz = xcd>>1, each XCD owns
// 4 j-tiles x 8 e-tiles of one batch half.
__global__ __launch_bounds__(512, 2) void gemm_pv256(
    const unsigned short* __restrict__ P, const unsigned short* __restrict__ Vt,
    const float* __restrict__ l, float* __restrict__ out)
{
    __shared__ unsigned short lds[49152];   // 96 KB
    const int orig = blockIdx.x;
    const int xcd  = orig & 7;
    const int pos  = orig >> 3;           // 0..31
    const int bz   = xcd >> 1;
    const long gm0 = (long)((xcd & 1) * 4 + (pos >> 3)) * 256;  // j
    const long gn0 = (long)(pos & 7) * 128;                     // e

    const unsigned short* Ab = P + (long)bz * 2048 * 2048 + gm0 * 2048;
    const unsigned short* Bb = Vt + gn0 * 8192 + (long)bz * 2048;

    f32x4 acc[8][2];
    pv256_core(Ab, Bb, lds, acc);

    const int tid = threadIdx.x;
    const int w = tid >> 6, lane = tid & 63;
    const int fr = lane & 15, quad = lane >> 4;
    const int wm = (w >> 2) * 128, wn = (w & 3) * 32;

    float* Ob = out + (long)bz * 2048 * 1024;
    const float* lb = l + (long)bz * 2048;
#pragma unroll
    for (int mi = 0; mi < 8; mi++) {
        const long rb = gm0 + wm + (mi >> 2) * 64 + (mi & 3) * 16 + quad * 4;
        float inv[4];
#pragma unroll
        for (int rr = 0; rr < 4; rr++) inv[rr] = 1.0f / lb[rb + rr];
#pragma unroll
        for (int nj = 0; nj < 2; nj++) {
            const long cb = gn0 + wn + nj * 16 + fr;
#pragma unroll
            for (int rr = 0; rr < 4; rr++)
                Ob[(rb + rr) * 1024L + cb] = acc[mi][nj][rr] * inv[rr];
        }
    }
}

// Fused prep: [0,8192) convert x; [8192,8192+3072) transpose weights;
// block 11264 zeroes l (8192 floats).
__global__ __launch_bounds__(256) void prep(
    const float* __restrict__ x,
    const float* __restrict__ Wq, const float* __restrict__ Wk,
    const float* __restrict__ Wv,
    unsigned short* __restrict__ xb, unsigned short* __restrict__ Wqkvt,
    float* __restrict__ l)
{
    __shared__ float t[32][33];
    const int b = blockIdx.x;
    const int tid = threadIdx.x;
    if (b < 8192) {
        int i = b * 256 + tid;
        float4 v = ((const float4*)x)[i];
        ushort4 o;
        o.x = f2bf(v.x); o.y = f2bf(v.y); o.z = f2bf(v.z); o.w = f2bf(v.w);
        ((ushort4*)xb)[i] = o;
        return;
    }
    if (b == 8192 + 3072) {
        float4 z = {0.f, 0.f, 0.f, 0.f};
#pragma unroll
        for (int i = 0; i < 8; i++)
            ((float4*)l)[tid * 8 + i] = z;
        return;
    }
    int tix = b - 8192;
    const int w = tix >> 10;
    tix &= 1023;
    const float* W = (w == 0) ? Wq : (w == 1) ? Wk : Wv;
    unsigned short* Wt = Wqkvt + (long)w * 1024 * 1024;
    const int bx = (tix & 31) * 32;
    const int by = (tix >> 5) * 32;
    const int tx = tid & 31;
    const int ty = (tid >> 5) * 4;
#pragma unroll
    for (int j = 0; j < 4; j++)
        t[ty + j][tx] = W[(long)(by + ty + j) * 1024 + bx + tx];
    __syncthreads();
#pragma unroll
    for (int j = 0; j < 4; j++)
        Wt[(long)(bx + ty + j) * 1024 + by + tx] = f2bf(t[tx][ty + j]);
}

extern "C" void kernel_launch(void* const* d_in, const int* in_sizes, int n_in,
                              void* d_out, int out_size, void* d_ws,
                              size_t ws_size, hipStream_t stream)
{
    const float* x  = (const float*)d_in[0];
    const float* Wq = (const float*)d_in[1];
    const float* Wk = (const float*)d_in[2];
    const float* Wv = (const float*)d_in[3];
    float* out = (float*)d_out;

    const long M1 = 1024 * 1024;
    unsigned short* u     = (unsigned short*)d_ws;
    unsigned short* xb    = u;                  // 8M
    unsigned short* Wqkvt = u + 8 * M1;         // 3M
    unsigned short* QKb   = Wqkvt + 3 * M1;     // 16M [8192 x 2048]
    unsigned short* Vtb   = QKb + 16 * M1;      // 8M  [1024 x 8192]
    unsigned short* Pb    = Vtb + 8 * M1;       // 16M [4 x 2048 x 2048]
    float* l              = (float*)(Pb + 16 * M1);  // 8192 f32

    prep<<<dim3(8192 + 3072 + 1), dim3(256), 0, stream>>>(x, Wq, Wk, Wv, xb, Wqkvt, l);

    // Q/K: [8192x1024] @ [2048x1024]^T, 256 blocks exact
    gemm_qk256<<<dim3(256), dim3(512), 0, stream>>>(xb, Wqkvt, QKb);

    // V: [8192x1024] @ [1024x1024]^T -> Vt (transposed), 256 blocks exact
    gemm_v128<<<dim3(256), dim3(512), 0, stream>>>(xb, Wqkvt + 2 * M1, Vtb);

    // P'[j,i] = exp((K_j.Q_i)/32) bf16, + row sums l, 256^2 8-phase
    gemm_scores256<<<dim3(256), dim3(512), 0, stream>>>(QKb, Pb, l);

    // out = (P' @ V) / l, 256x128 8-phase, 256 blocks exact
    gemm_pv256<<<dim3(256), dim3(512), 0, stream>>>(Pb, Vtb, l, out);
}

// Round 11
// 217.177 us; speedup vs baseline: 1.7919x; 1.0175x over previous
//
#include <hip/hip_runtime.h>
#include <math.h>

// SelfAttentionLayer B=4, N=2048, D=E=1024, fp32 in/out.
// out[b,j,e] = sum_i softmax_i(q_i . k_j / 32) * v[b,i,e]
// R15: transposed-operand epilogues for qk + scores (Vt-store pattern,
//      proven R11-R13). scores: A=Q,B=K -> C[i,j]; P[j][i] written as
//      ushort4 (32 stores vs 128 scalar); l[j] sum becomes lane-local
//      (8 shuffles + 4 atomics vs 128 + 16). qk: A=W,B=x -> C[f,m];
//      QK[m][f] as ushort4. Cores byte-identical (refcheck'd 3-4x);
//      v128/pv/prep unchanged from R14 (passed, 221.0us; scores was top
//      dispatch 61us MfmaUtil 21% with epilogue-heavy profile).
//
// ws (ushort): xb[8M] Wqkvt[3M] QKb[16M] Vtb[8M] Pb[16M] l[8192 f32].

typedef __bf16 bf16x8 __attribute__((ext_vector_type(8)));
typedef float f32x4 __attribute__((ext_vector_type(4)));

static __device__ __forceinline__ unsigned short f2bf(float f) {
    unsigned u = __float_as_uint(f);
    u += 0x7fff + ((u >> 16) & 1);   // round-to-nearest-even
    return (unsigned short)(u >> 16);
}

#define GLDS16(gptr, lptr)                                                            \
    __builtin_amdgcn_global_load_lds(                                                 \
        (const __attribute__((address_space(1))) void*)(gptr),                        \
        (__attribute__((address_space(3))) void*)(lptr), 16, 0, 0)

#define BARSYNC  __builtin_amdgcn_s_barrier()
#define WAITLGKM do { asm volatile("s_waitcnt lgkmcnt(0)" ::: "memory");    \
                      __builtin_amdgcn_sched_barrier(0); } while (0)

// ===================== 256x256 8-phase GEMM core =====================
// (R11-R14 structure, proven: conflicts 0, passed refcheck 4x.)
// LDS 128KiB ushort map: A[buf][256][64] at buf*16384; B at 32768+buf*16384.
// Stage units: A(mh) rows {0,128}+mh*64..+63 ; B(nh) rows {0,64,128,192}+nh*32..+31
// Schedule (iter i: buf0=tile 2i, buf1=2i+1; t1=2i+1,t2=2i+2,t3=2i+3):
//  ph1(0,0,0):ldA0+ldB->bfA, STG_B(t1,0,b1)  ph5(1,0,0): same, STG_A(t2,1,b0)
//  ph2(0,0,1):ldB->bfB,      STG_A(t1,1,b1)  ph6(1,0,1): ldB->bfB, STG_B(t2,0,b0)
//  ph3(0,1,1):ldA1,          STG_A(t2,0,b0)  ph7(1,1,1): ldA1,     STG_A(t3,0,b1)
//  ph4(0,1,0):(no reads),    STG_B(t2,1,b0)  ph8(1,1,0): (none),   STG_B(t3,1,b1)
//  WAITV(4) after ph4/ph8 MFMA. Every stage >=1 close-barrier after last read.
__device__ __forceinline__ void gemm256_core(
    const unsigned short* __restrict__ Ab,   // + gm0*ld
    const unsigned short* __restrict__ Bb,   // + gn0*ld
    const long ld, unsigned short* lds, f32x4 acc[8][4])
{
    const int tid  = threadIdx.x;
    const int w    = tid >> 6;
    const int lane = tid & 63;

    const int r  = lane >> 3;
    const int s  = lane & 7;
    const int cg = (s ^ r) * 8;

    const int fr    = lane & 15;
    const int quad  = lane >> 4;
    const int sw    = fr & 7;
    const int arow0 = (w >> 2) * 128;
    const int brow0 = (w & 3) * 64;

#define STG_A(t, mh, buf) do {                                              \
    const int rb_ = (w >> 2) * 128 + (mh) * 64 + (w & 3) * 16;              \
    const unsigned short* g_ = Ab + (long)(rb_ + r) * ld + (long)(t) * 64 + cg; \
    unsigned short* d_ = lds + (buf) * 16384 + rb_ * 64;                    \
    GLDS16(g_, d_); GLDS16(g_ + 8 * ld, d_ + 512); } while (0)
#define STG_B(t, nh, buf) do {                                              \
    const int rb_ = (w >> 1) * 64 + (nh) * 32 + (w & 1) * 16;               \
    const unsigned short* g_ = Bb + (long)(rb_ + r) * ld + (long)(t) * 64 + cg; \
    unsigned short* d_ = lds + 32768 + (buf) * 16384 + rb_ * 64;            \
    GLDS16(g_, d_); GLDS16(g_ + 8 * ld, d_ + 512); } while (0)

    bf16x8 af[4][2], bfA[2][2], bfB[2][2];
#define LOADA(buf, mh) do {                                                 \
    _Pragma("unroll") for (int ks_ = 0; ks_ < 2; ks_++)                     \
    _Pragma("unroll") for (int i_ = 0; i_ < 4; i_++)                        \
        af[i_][ks_] = *(const bf16x8*)&lds[(buf) * 16384 +                  \
            (arow0 + (mh) * 64 + i_ * 16 + fr) * 64 +                       \
            ((ks_ * 4 + quad) ^ sw) * 8]; } while (0)
#define LOADB(BF, buf, nh) do {                                             \
    _Pragma("unroll") for (int ks_ = 0; ks_ < 2; ks_++)                     \
    _Pragma("unroll") for (int j_ = 0; j_ < 2; j_++)                        \
        BF[j_][ks_] = *(const bf16x8*)&lds[32768 + (buf) * 16384 +          \
            (brow0 + (nh) * 32 + j_ * 16 + fr) * 64 +                       \
            ((ks_ * 4 + quad) ^ sw) * 8]; } while (0)

#define MFMA16(mh, nh, BF) do {                                             \
    __builtin_amdgcn_s_setprio(1);                                          \
    _Pragma("unroll") for (int ks_ = 0; ks_ < 2; ks_++)                     \
    _Pragma("unroll") for (int i_ = 0; i_ < 4; i_++)                        \
    _Pragma("unroll") for (int j_ = 0; j_ < 2; j_++)                        \
        acc[(mh) * 4 + i_][(nh) * 2 + j_] =                                 \
            __builtin_amdgcn_mfma_f32_16x16x32_bf16(                        \
                af[i_][ks_], BF[j_][ks_],                                   \
                acc[(mh) * 4 + i_][(nh) * 2 + j_], 0, 0, 0);                \
    __builtin_amdgcn_s_setprio(0); } while (0)

#pragma unroll
    for (int i = 0; i < 8; i++)
#pragma unroll
        for (int j = 0; j < 4; j++) acc[i][j] = f32x4{0.f, 0.f, 0.f, 0.f};

    // prologue: buf0 <- tile0 (4 units); buf1 <- tile1 partial (mh0, nh1)
    STG_A(0, 0, 0); STG_A(0, 1, 0); STG_B(0, 0, 0); STG_B(0, 1, 0);
    STG_A(1, 0, 1); STG_B(1, 1, 1);
    asm volatile("s_waitcnt vmcnt(4)" ::: "memory");   // buf0 complete
    BARSYNC;

#pragma unroll 1
    for (int i = 0; i < 8; ++i) {
        const int t1 = 2 * i + 1;
        const int t2 = (2 * i + 2) & 15;   // dummy re-read on last iter (safe)
        const int t3 = (2 * i + 3) & 15;
        // ph1 (buf0, mh0, nh0)
        LOADA(0, 0); LOADB(bfA, 0, 0); STG_B(t1, 0, 1);
        BARSYNC; WAITLGKM; MFMA16(0, 0, bfA); BARSYNC;
        // ph2 (buf0, mh0, nh1)
        LOADB(bfB, 0, 1); STG_A(t1, 1, 1);
        BARSYNC; WAITLGKM; MFMA16(0, 1, bfB); BARSYNC;
        // ph3 (buf0, mh1, nh1)
        LOADA(0, 1); STG_A(t2, 0, 0);
        BARSYNC; WAITLGKM; MFMA16(1, 1, bfB); BARSYNC;
        // ph4 (buf0, mh1, nh0) reuses bfA + drain: buf1 <- t1 complete
        STG_B(t2, 1, 0);
        BARSYNC; MFMA16(1, 0, bfA);
        asm volatile("s_waitcnt vmcnt(4)" ::: "memory"); BARSYNC;
        // ph5 (buf1, mh0, nh0)
        LOADA(1, 0); LOADB(bfA, 1, 0); STG_A(t2, 1, 0);
        BARSYNC; WAITLGKM; MFMA16(0, 0, bfA); BARSYNC;
        // ph6 (buf1, mh0, nh1)
        LOADB(bfB, 1, 1); STG_B(t2, 0, 0);
        BARSYNC; WAITLGKM; MFMA16(0, 1, bfB); BARSYNC;
        // ph7 (buf1, mh1, nh1)
        LOADA(1, 1); STG_A(t3, 0, 1);
        BARSYNC; WAITLGKM; MFMA16(1, 1, bfB); BARSYNC;
        // ph8 (buf1, mh1, nh0) reuses bfA + drain: buf0 <- t2 complete
        STG_B(t3, 1, 1);
        BARSYNC; MFMA16(1, 0, bfA);
        asm volatile("s_waitcnt vmcnt(4)" ::: "memory"); BARSYNC;
    }
    asm volatile("s_waitcnt vmcnt(0)" ::: "memory");   // drain dummy stages

#undef STG_A
#undef STG_B
#undef LOADA
#undef LOADB
#undef MFMA16
}

// ===================== 128x256 8-phase V core =====================
// (R14 structure, passed refcheck.) A = xb (128 m-rows, ld 1024),
// B = Wvt (256 e-rows, ld 1024). K = 1024. LDS 96KB. WAITV(3) at ph4/ph8.
__device__ __forceinline__ void gemm_v128_core(
    const unsigned short* __restrict__ Ab,   // xb + gm0*1024
    const unsigned short* __restrict__ Bb,   // Wvt + gn0*1024
    unsigned short* lds, f32x4 acc[4][4])
{
    const int tid  = threadIdx.x;
    const int w    = tid >> 6;
    const int lane = tid & 63;

    const int r  = lane >> 3;
    const int s  = lane & 7;
    const int cg = (s ^ r) * 8;

    const int fr    = lane & 15;
    const int quad  = lane >> 4;
    const int sw    = fr & 7;
    const int arow0 = (w >> 2) * 64;
    const int brow0 = (w & 3) * 64;

#define STG_VA(t, mh, buf) do {                                             \
    const int rb_ = (w >> 2) * 64 + (mh) * 32 + (w & 3) * 8;                \
    const unsigned short* g_ = Ab + (long)(rb_ + r) * 1024 + (long)(t) * 64 + cg; \
    unsigned short* d_ = lds + (buf) * 8192 + rb_ * 64;                     \
    GLDS16(g_, d_); } while (0)
#define STG_VB(t, nh, buf) do {                                             \
    const int rb_ = (w >> 1) * 64 + (nh) * 32 + (w & 1) * 16;               \
    const unsigned short* g_ = Bb + (long)(rb_ + r) * 1024 + (long)(t) * 64 + cg; \
    unsigned short* d_ = lds + 16384 + (buf) * 16384 + rb_ * 64;            \
    GLDS16(g_, d_); GLDS16(g_ + 8 * 1024, d_ + 512); } while (0)

    bf16x8 af[2][2], bfA[2][2], bfB[2][2];
#define LOADVA(buf, mh) do {                                                \
    _Pragma("unroll") for (int ks_ = 0; ks_ < 2; ks_++)                     \
    _Pragma("unroll") for (int i_ = 0; i_ < 2; i_++)                        \
        af[i_][ks_] = *(const bf16x8*)&lds[(buf) * 8192 +                   \
            (arow0 + (mh) * 32 + i_ * 16 + fr) * 64 +                       \
            ((ks_ * 4 + quad) ^ sw) * 8]; } while (0)
#define LOADVB(BF, buf, nh) do {                                            \
    _Pragma("unroll") for (int ks_ = 0; ks_ < 2; ks_++)                     \
    _Pragma("unroll") for (int j_ = 0; j_ < 2; j_++)                        \
        BF[j_][ks_] = *(const bf16x8*)&lds[16384 + (buf) * 16384 +          \
            (brow0 + (nh) * 32 + j_ * 16 + fr) * 64 +                       \
            ((ks_ * 4 + quad) ^ sw) * 8]; } while (0)

#define MFMA_V(mh, nh, BF) do {                                             \
    __builtin_amdgcn_s_setprio(1);                                          \
    _Pragma("unroll") for (int ks_ = 0; ks_ < 2; ks_++)                     \
    _Pragma("unroll") for (int i_ = 0; i_ < 2; i_++)                        \
    _Pragma("unroll") for (int j_ = 0; j_ < 2; j_++)                        \
        acc[(mh) * 2 + i_][(nh) * 2 + j_] =                                 \
            __builtin_amdgcn_mfma_f32_16x16x32_bf16(                        \
                af[i_][ks_], BF[j_][ks_],                                   \
                acc[(mh) * 2 + i_][(nh) * 2 + j_], 0, 0, 0);                \
    __builtin_amdgcn_s_setprio(0); } while (0)

#pragma unroll
    for (int i = 0; i < 4; i++)
#pragma unroll
        for (int j = 0; j < 4; j++) acc[i][j] = f32x4{0.f, 0.f, 0.f, 0.f};

    // prologue: buf0 <- tile0 (6 loads); buf1 <- tile1 partial (A-mh0 1, B-nh1 2)
    STG_VA(0, 0, 0); STG_VA(0, 1, 0); STG_VB(0, 0, 0); STG_VB(0, 1, 0);
    STG_VA(1, 0, 1); STG_VB(1, 1, 1);
    asm volatile("s_waitcnt vmcnt(3)" ::: "memory");   // buf0 complete
    BARSYNC;

#pragma unroll 1
    for (int i = 0; i < 8; ++i) {
        const int t1 = 2 * i + 1;
        const int t2 = (2 * i + 2) & 15;   // dummy re-read on last iter (safe)
        const int t3 = (2 * i + 3) & 15;
        // ph1 (buf0, mh0, nh0)
        LOADVA(0, 0); LOADVB(bfA, 0, 0); STG_VB(t1, 0, 1);
        BARSYNC; WAITLGKM; MFMA_V(0, 0, bfA); BARSYNC;
        // ph2 (buf0, mh0, nh1)
        LOADVB(bfB, 0, 1); STG_VA(t1, 1, 1);
        BARSYNC; WAITLGKM; MFMA_V(0, 1, bfB); BARSYNC;
        // ph3 (buf0, mh1, nh1)
        LOADVA(0, 1); STG_VA(t2, 0, 0);
        BARSYNC; WAITLGKM; MFMA_V(1, 1, bfB); BARSYNC;
        // ph4 (buf0, mh1, nh0) reuses bfA + drain: buf1 <- t1 complete
        STG_VB(t2, 1, 0);
        BARSYNC; MFMA_V(1, 0, bfA);
        asm volatile("s_waitcnt vmcnt(3)" ::: "memory"); BARSYNC;
        // ph5 (buf1, mh0, nh0)
        LOADVA(1, 0); LOADVB(bfA, 1, 0); STG_VA(t2, 1, 0);
        BARSYNC; WAITLGKM; MFMA_V(0, 0, bfA); BARSYNC;
        // ph6 (buf1, mh0, nh1)
        LOADVB(bfB, 1, 1); STG_VB(t2, 0, 0);
        BARSYNC; WAITLGKM; MFMA_V(0, 1, bfB); BARSYNC;
        // ph7 (buf1, mh1, nh1)
        LOADVA(1, 1); STG_VA(t3, 0, 1);
        BARSYNC; WAITLGKM; MFMA_V(1, 1, bfB); BARSYNC;
        // ph8 (buf1, mh1, nh0) reuses bfA + drain: buf0 <- t2 complete
        STG_VB(t3, 1, 1);
        BARSYNC; MFMA_V(1, 0, bfA);
        asm volatile("s_waitcnt vmcnt(3)" ::: "memory"); BARSYNC;
    }
    asm volatile("s_waitcnt vmcnt(0)" ::: "memory");   // drain dummy stages

#undef STG_VA
#undef STG_VB
#undef LOADVA
#undef LOADVB
#undef MFMA_V
}

// ===================== 256x128 8-phase PV core =====================
// (R13/R14 structure, passed refcheck.) A = P rows (lda 2048), B = Vt rows
// (ldb 8192). K = 2048 (32 tiles). LDS 96KB. WAITV(3) at ph4/ph8.
__device__ __forceinline__ void pv256_core(
    const unsigned short* __restrict__ Ab,   // P + bz*4M + gm0*2048
    const unsigned short* __restrict__ Bb,   // Vt + gn0*8192 + bz*2048
    unsigned short* lds, f32x4 acc[8][2])
{
    const int tid  = threadIdx.x;
    const int w    = tid >> 6;
    const int lane = tid & 63;

    const int r  = lane >> 3;
    const int s  = lane & 7;
    const int cg = (s ^ r) * 8;

    const int fr    = lane & 15;
    const int quad  = lane >> 4;
    const int sw    = fr & 7;
    const int arow0 = (w >> 2) * 128;
    const int brow0 = (w & 3) * 32;

#define STG_PA(t, mh, buf) do {                                             \
    const int rb_ = (w >> 2) * 128 + (mh) * 64 + (w & 3) * 16;              \
    const unsigned short* g_ = Ab + (long)(rb_ + r) * 2048 + (long)(t) * 64 + cg; \
    unsigned short* d_ = lds + (buf) * 16384 + rb_ * 64;                    \
    GLDS16(g_, d_); GLDS16(g_ + 8 * 2048, d_ + 512); } while (0)
#define STG_PB(t, nh, buf) do {                                             \
    const int rb_ = (w & 3) * 32 + (nh) * 16 + (w >> 2) * 8;                \
    const unsigned short* g_ = Bb + (long)(rb_ + r) * 8192 + (long)(t) * 64 + cg; \
    unsigned short* d_ = lds + 32768 + (buf) * 8192 + rb_ * 64;             \
    GLDS16(g_, d_); } while (0)

    bf16x8 af[4][2], bfA[2], bfB[2];
#define LOADPA(buf, mh) do {                                                \
    _Pragma("unroll") for (int ks_ = 0; ks_ < 2; ks_++)                     \
    _Pragma("unroll") for (int i_ = 0; i_ < 4; i_++)                        \
        af[i_][ks_] = *(const bf16x8*)&lds[(buf) * 16384 +                  \
            (arow0 + (mh) * 64 + i_ * 16 + fr) * 64 +                       \
            ((ks_ * 4 + quad) ^ sw) * 8]; } while (0)
#define LOADPB(BF, buf, nh) do {                                            \
    _Pragma("unroll") for (int ks_ = 0; ks_ < 2; ks_++)                     \
        BF[ks_] = *(const bf16x8*)&lds[32768 + (buf) * 8192 +               \
            (brow0 + (nh) * 16 + fr) * 64 +                                 \
            ((ks_ * 4 + quad) ^ sw) * 8]; } while (0)

#define MFMA8(mh, nh, BF) do {                                              \
    __builtin_amdgcn_s_setprio(1);                                          \
    _Pragma("unroll") for (int ks_ = 0; ks_ < 2; ks_++)                     \
    _Pragma("unroll") for (int i_ = 0; i_ < 4; i_++)                        \
        acc[(mh) * 4 + i_][nh] = __builtin_amdgcn_mfma_f32_16x16x32_bf16(   \
            af[i_][ks_], BF[ks_], acc[(mh) * 4 + i_][nh], 0, 0, 0);         \
    __builtin_amdgcn_s_setprio(0); } while (0)

#pragma unroll
    for (int i = 0; i < 8; i++)
#pragma unroll
        for (int j = 0; j < 2; j++) acc[i][j] = f32x4{0.f, 0.f, 0.f, 0.f};

    // prologue: buf0 <- tile0 (6 loads); buf1 <- tile1 partial (A-mh0 2, B-nh1 1)
    STG_PA(0, 0, 0); STG_PA(0, 1, 0); STG_PB(0, 0, 0); STG_PB(0, 1, 0);
    STG_PA(1, 0, 1); STG_PB(1, 1, 1);
    asm volatile("s_waitcnt vmcnt(3)" ::: "memory");   // buf0 complete
    BARSYNC;

#pragma unroll 1
    for (int i = 0; i < 16; ++i) {
        const int t1 = 2 * i + 1;
        const int t2 = (2 * i + 2) & 31;   // dummy re-read on last iter (safe)
        const int t3 = (2 * i + 3) & 31;
        // ph1 (buf0, mh0, nh0)
        LOADPA(0, 0); LOADPB(bfA, 0, 0); STG_PB(t1, 0, 1);
        BARSYNC; WAITLGKM; MFMA8(0, 0, bfA); BARSYNC;
        // ph2 (buf0, mh0, nh1)
        LOADPB(bfB, 0, 1); STG_PA(t1, 1, 1);
        BARSYNC; WAITLGKM; MFMA8(0, 1, bfB); BARSYNC;
        // ph3 (buf0, mh1, nh1)
        LOADPA(0, 1); STG_PA(t2, 0, 0);
        BARSYNC; WAITLGKM; MFMA8(1, 1, bfB); BARSYNC;
        // ph4 (buf0, mh1, nh0) reuses bfA + drain: buf1 <- t1 complete
        STG_PB(t2, 1, 0);
        BARSYNC; MFMA8(1, 0, bfA);
        asm volatile("s_waitcnt vmcnt(3)" ::: "memory"); BARSYNC;
        // ph5 (buf1, mh0, nh0)
        LOADPA(1, 0); LOADPB(bfA, 1, 0); STG_PA(t2, 1, 0);
        BARSYNC; WAITLGKM; MFMA8(0, 0, bfA); BARSYNC;
        // ph6 (buf1, mh0, nh1)
        LOADPB(bfB, 1, 1); STG_PB(t2, 0, 0);
        BARSYNC; WAITLGKM; MFMA8(0, 1, bfB); BARSYNC;
        // ph7 (buf1, mh1, nh1)
        LOADPA(1, 1); STG_PA(t3, 0, 1);
        BARSYNC; WAITLGKM; MFMA8(1, 1, bfB); BARSYNC;
        // ph8 (buf1, mh1, nh0) reuses bfA + drain: buf0 <- t2 complete
        STG_PB(t3, 1, 1);
        BARSYNC; MFMA8(1, 0, bfA);
        asm volatile("s_waitcnt vmcnt(3)" ::: "memory"); BARSYNC;
    }
    asm volatile("s_waitcnt vmcnt(0)" ::: "memory");   // drain dummy stages

#undef STG_PA
#undef STG_PB
#undef LOADPA
#undef LOADPB
#undef MFMA8
}

// ---------------- Q/K GEMM (swapped: A=W rows, B=x rows) -------------------
// C[f, m]: f = qk-feature (0..2047), m = token. Lane holds 4 consecutive f
// at one m -> ushort4 store to QK[m*2048 + f]. 256 blocks exact.
// XCD swizzle: each XCD owns 4 token-panels x all 8 f-tiles (6MB).
__global__ __launch_bounds__(512, 2) void gemm_qk256(
    const unsigned short* __restrict__ X, const unsigned short* __restrict__ W,
    unsigned short* __restrict__ QK)
{
    __shared__ unsigned short lds[65536];
    const int orig = blockIdx.x;
    const int xcd  = orig & 7;
    const int pos  = orig >> 3;           // 0..31
    const long gm0 = (long)(pos >> 2) * 256;            // feature f
    const long gn0 = (long)(xcd * 4 + (pos & 3)) * 256; // token m

    f32x4 acc[8][4];
    gemm256_core(W + gm0 * 1024, X + gn0 * 1024, 1024, lds, acc);

    const int tid = threadIdx.x;
    const int w = tid >> 6, lane = tid & 63;
    const int fr = lane & 15, quad = lane >> 4;
    const int wm = (w >> 2) * 128, wn = (w & 3) * 64;

#pragma unroll
    for (int mi = 0; mi < 8; mi++) {
        const long rb = gm0 + wm + (mi >> 2) * 64 + (mi & 3) * 16 + quad * 4;  // f
#pragma unroll
        for (int n = 0; n < 4; n++) {
            const long cb = gn0 + wn + n * 16 + fr;                            // m
            ushort4 o;
            o.x = f2bf(acc[mi][n][0]);
            o.y = f2bf(acc[mi][n][1]);
            o.z = f2bf(acc[mi][n][2]);
            o.w = f2bf(acc[mi][n][3]);
            *(ushort4*)&QK[cb * 2048L + rb] = o;
        }
    }
}

// ---------------- V GEMM (128x256 8-phase, 256 blocks exact) ---------------
// (R14, passed.) A = xb [8192x1024]; B = Wvt [1024x1024]. Vt[e*8192+m] bf16.
__global__ __launch_bounds__(512, 2) void gemm_v128(
    const unsigned short* __restrict__ A, const unsigned short* __restrict__ B,
    unsigned short* __restrict__ Vt)
{
    __shared__ unsigned short lds[49152];   // 96 KB
    const int orig = blockIdx.x;
    const int xcd  = orig & 7;
    const int pos  = orig >> 3;           // 0..31
    const long gm0 = (long)(xcd * 8 + (pos & 7)) * 128;
    const long gn0 = (long)(pos >> 3) * 256;

    f32x4 acc[4][4];
    gemm_v128_core(A + gm0 * 1024, B + gn0 * 1024, lds, acc);

    const int tid = threadIdx.x;
    const int w = tid >> 6, lane = tid & 63;
    const int fr = lane & 15, quad = lane >> 4;
    const int wm = (w >> 2) * 64, wn = (w & 3) * 64;

#pragma unroll
    for (int ai = 0; ai < 4; ai++) {
        const long rb = gm0 + wm + ai * 16 + quad * 4;
#pragma unroll
        for (int aj = 0; aj < 4; aj++) {
            const long ce = gn0 + wn + aj * 16 + fr;
            ushort4 o;
            o.x = f2bf(acc[ai][aj][0]);
            o.y = f2bf(acc[ai][aj][1]);
            o.z = f2bf(acc[ai][aj][2]);
            o.w = f2bf(acc[ai][aj][3]);
            *(ushort4*)&Vt[ce * 8192L + rb] = o;
        }
    }
}

// ------------- scores GEMM (swapped: A=Q rows i, B=K rows j) ---------------
// C[i, j] = Q_i . K_j. Lane holds 4 consecutive i at one j -> ushort4 store
// to P[j*2048 + i]. l[j] = sum_i exp: lane-local over 32 regs per n, then
// 2 quad-shuffles + 1 atomic (quad==0). 256 blocks exact.
__global__ __launch_bounds__(512, 2) void gemm_scores256(
    const unsigned short* __restrict__ QKb, unsigned short* __restrict__ P,
    float* __restrict__ l)
{
    __shared__ unsigned short lds[65536];
    const int orig = blockIdx.x;
    const int xcd  = orig & 7;
    const int pos  = orig >> 3;           // 0..31
    const int bz   = xcd >> 1;
    const long gm0 = (long)((xcd & 1) * 4 + (pos >> 3)) * 256;  // i (Q rows)
    const long gn0 = (long)(pos & 7) * 256;                     // j (K rows)

    const unsigned short* Ab = QKb + (long)bz * 2048 * 2048 + gm0 * 2048;         // Q
    const unsigned short* Bb = QKb + (long)bz * 2048 * 2048 + 1024 + gn0 * 2048;  // K

    f32x4 acc[8][4];
    gemm256_core(Ab, Bb, 2048, lds, acc);

    const int tid = threadIdx.x;
    const int w = tid >> 6, lane = tid & 63;
    const int fr = lane & 15, quad = lane >> 4;
    const int wm = (w >> 2) * 128, wn = (w & 3) * 64;

    unsigned short* Pb = P + (long)bz * 2048 * 2048;
    float* lb = l + (long)bz * 2048;
    const float scale = 1.0f / 32.0f;

    float colsum[4] = {0.f, 0.f, 0.f, 0.f};
#pragma unroll
    for (int mi = 0; mi < 8; mi++) {
        const long rb = gm0 + wm + (mi >> 2) * 64 + (mi & 3) * 16 + quad * 4;  // i
#pragma unroll
        for (int n = 0; n < 4; n++) {
            const long cb = gn0 + wn + n * 16 + fr;                            // j
            float e0 = __expf(acc[mi][n][0] * scale);
            float e1 = __expf(acc[mi][n][1] * scale);
            float e2 = __expf(acc[mi][n][2] * scale);
            float e3 = __expf(acc[mi][n][3] * scale);
            colsum[n] += (e0 + e1) + (e2 + e3);
            ushort4 o;
            o.x = f2bf(e0); o.y = f2bf(e1); o.z = f2bf(e2); o.w = f2bf(e3);
            *(ushort4*)&Pb[cb * 2048L + rb] = o;
        }
    }
    // combine the 4 quads (same j across quads), then one atomic per (w, fr, n)
#pragma unroll
    for (int n = 0; n < 4; n++) {
        colsum[n] += __shfl_xor(colsum[n], 16);
        colsum[n] += __shfl_xor(colsum[n], 32);
    }
    if (quad == 0) {
#pragma unroll
        for (int n = 0; n < 4; n++)
            atomicAdd(&lb[gn0 + wn + n * 16 + fr], colsum[n]);
    }
}

// ---------------- PV GEMM (256x128 8-phase): out = (P' @ V)/l ------------
// (R13/R14, passed.) Grid 256 exact. XCD swizzle: bz = xcd>>1.
__global__ __launch_bounds__(512, 2) void gemm_pv256(
    const unsigned short* __restrict__ P, const unsigned short* __restrict__ Vt,
    const float* __restrict__ l, float* __restrict__ out)
{
    __shared__ unsigned short lds[49152];   // 96 KB
    const int orig = blockIdx.x;
    const int xcd  = orig & 7;
    const int pos  = orig >> 3;           // 0..31
    const int bz   = xcd >> 1;
    const long gm0 = (long)((xcd & 1) * 4 + (pos >> 3)) * 256;  // j
    const long gn0 = (long)(pos & 7) * 128;                     // e

    const unsigned short* Ab = P + (long)bz * 2048 * 2048 + gm0 * 2048;
    const unsigned short* Bb = Vt + gn0 * 8192 + (long)bz * 2048;

    f32x4 acc[8][2];
    pv256_core(Ab, Bb, lds, acc);

    const int tid = threadIdx.x;
    const int w = tid >> 6, lane = tid & 63;
    const int fr = lane & 15, quad = lane >> 4;
    const int wm = (w >> 2) * 128, wn = (w & 3) * 32;

    float* Ob = out + (long)bz * 2048 * 1024;
    const float* lb = l + (long)bz * 2048;
#pragma unroll
    for (int mi = 0; mi < 8; mi++) {
        const long rb = gm0 + wm + (mi >> 2) * 64 + (mi & 3) * 16 + quad * 4;
        float inv[4];
#pragma unroll
        for (int rr = 0; rr < 4; rr++) inv[rr] = 1.0f / lb[rb + rr];
#pragma unroll
        for (int nj = 0; nj < 2; nj++) {
            const long cb = gn0 + wn + nj * 16 + fr;
#pragma unroll
            for (int rr = 0; rr < 4; rr++)
                Ob[(rb + rr) * 1024L + cb] = acc[mi][nj][rr] * inv[rr];
        }
    }
}

// Fused prep: [0,8192) convert x; [8192,8192+3072) transpose weights;
// block 11264 zeroes l (8192 floats).
__global__ __launch_bounds__(256) void prep(
    const float* __restrict__ x,
    const float* __restrict__ Wq, const float* __restrict__ Wk,
    const float* __restrict__ Wv,
    unsigned short* __restrict__ xb, unsigned short* __restrict__ Wqkvt,
    float* __restrict__ l)
{
    __shared__ float t[32][33];
    const int b = blockIdx.x;
    const int tid = threadIdx.x;
    if (b < 8192) {
        int i = b * 256 + tid;
        float4 v = ((const float4*)x)[i];
        ushort4 o;
        o.x = f2bf(v.x); o.y = f2bf(v.y); o.z = f2bf(v.z); o.w = f2bf(v.w);
        ((ushort4*)xb)[i] = o;
        return;
    }
    if (b == 8192 + 3072) {
        float4 z = {0.f, 0.f, 0.f, 0.f};
#pragma unroll
        for (int i = 0; i < 8; i++)
            ((float4*)l)[tid * 8 + i] = z;
        return;
    }
    int tix = b - 8192;
    const int w = tix >> 10;
    tix &= 1023;
    const float* W = (w == 0) ? Wq : (w == 1) ? Wk : Wv;
    unsigned short* Wt = Wqkvt + (long)w * 1024 * 1024;
    const int bx = (tix & 31) * 32;
    const int by = (tix >> 5) * 32;
    const int tx = tid & 31;
    const int ty = (tid >> 5) * 4;
#pragma unroll
    for (int j = 0; j < 4; j++)
        t[ty + j][tx] = W[(long)(by + ty + j) * 1024 + bx + tx];
    __syncthreads();
#pragma unroll
    for (int j = 0; j < 4; j++)
        Wt[(long)(bx + ty + j) * 1024 + by + tx] = f2bf(t[tx][ty + j]);
}

extern "C" void kernel_launch(void* const* d_in, const int* in_sizes, int n_in,
                              void* d_out, int out_size, void* d_ws,
                              size_t ws_size, hipStream_t stream)
{
    const float* x  = (const float*)d_in[0];
    const float* Wq = (const float*)d_in[1];
    const float* Wk = (const float*)d_in[2];
    const float* Wv = (const float*)d_in[3];
    float* out = (float*)d_out;

    const long M1 = 1024 * 1024;
    unsigned short* u     = (unsigned short*)d_ws;
    unsigned short* xb    = u;                  // 8M
    unsigned short* Wqkvt = u + 8 * M1;         // 3M
    unsigned short* QKb   = Wqkvt + 3 * M1;     // 16M [8192 x 2048]
    unsigned short* Vtb   = QKb + 16 * M1;      // 8M  [1024 x 8192]
    unsigned short* Pb    = Vtb + 8 * M1;       // 16M [4 x 2048 x 2048]
    float* l              = (float*)(Pb + 16 * M1);  // 8192 f32

    prep<<<dim3(8192 + 3072 + 1), dim3(256), 0, stream>>>(x, Wq, Wk, Wv, xb, Wqkvt, l);

    // Q/K: C[f,m] = (Wqk row f) . (x row m), transposed-store to QK[m][f]
    gemm_qk256<<<dim3(256), dim3(512), 0, stream>>>(xb, Wqkvt, QKb);

    // V: [8192x1024] @ [1024x1024]^T -> Vt (transposed), 256 blocks exact
    gemm_v128<<<dim3(256), dim3(512), 0, stream>>>(xb, Wqkvt + 2 * M1, Vtb);

    // scores: C[i,j] = Q_i.K_j, exp, transposed-store to P[j][i], l[j] sums
    gemm_scores256<<<dim3(256), dim3(512), 0, stream>>>(QKb, Pb, l);

    // out = (P' @ V) / l, 256x128 8-phase, 256 blocks exact
    gemm_pv256<<<dim3(256), dim3(512), 0, stream>>>(Pb, Vtb, l, out);
}